// Round 4
// baseline (930.734 us; speedup 1.0000x reference)
//
#include <hip/hip_runtime.h>

#define DEV __device__ __forceinline__

typedef __bf16 bf16x8 __attribute__((ext_vector_type(8)));
typedef float f32x4 __attribute__((ext_vector_type(4)));
typedef unsigned short u16;
typedef u16 u16x4 __attribute__((ext_vector_type(4)));

constexpr int T_ANS = 32768;        // N*La answer tokens
constexpr int LQ    = 64;
constexpr int M_ALL = T_ANS + LQ;   // 32832 rows fed to projection
constexpr int M_PAD = 33024;        // 129*256 (256-tile padded)
constexpr int DIM   = 1024;

DEV u16 f2bf(float x) {
  unsigned u = __float_as_uint(x);
  return (u16)((u + 0x7FFFu + ((u >> 16) & 1u)) >> 16);
}
DEV float bf2f(u16 s) { return __uint_as_float(((unsigned)s) << 16); }

DEV void gl2lds16(const void* g, void* l) {
  __builtin_amdgcn_global_load_lds(
      (const __attribute__((address_space(1))) unsigned int*)g,
      (__attribute__((address_space(3))) unsigned int*)l, 16, 0, 0);
}

#define MF(A, B, C) __builtin_amdgcn_mfma_f32_16x16x32_bf16(A, B, C, 0, 0, 0)

// ---------------- 8-phase 256x256 GEMM core helpers ----------------
// LDS layout: [A0 32K][B0 32K][A1 32K][B1 32K] (dynamic, 128 KiB).
// Tile rows stored 128 B each; swizzle: byte ^= ((row&7)<<4).
// gl2lds dest is LINEAR; global source col-block is inverse-XOR'd (rule 21).

DEV void stageC(const char* gk, char* ldsT, int row0, int tid) {
  const int f = tid << 4;                 // 0..8191, 64 rows per chunk
  const int r = row0 + (f >> 7);
  const int cb = ((f >> 4) & 7) ^ (r & 7);
  gl2lds16(gk + (size_t)r * 2048 + (cb << 4), ldsT + (row0 << 7) + f);
}

DEV bf16x8 LF(const char* ldsT, int row, int cbyte) {
  return *(const bf16x8*)(ldsT + (row << 7) + (cbyte ^ ((row & 7) << 4)));
}

// One phase: ds-read 12 frags, issue stages, barrier, lgkm(0), 16 MFMA, [vm wait], barrier.
#define PH(Q, LA, LB, STAGES, VMW)                                                     \
  {                                                                                    \
    bf16x8 a00 = LF(LA, wm + (2*(Q))*16 + lr, hi16);                                   \
    bf16x8 a01 = LF(LA, wm + (2*(Q))*16 + lr, 64 + hi16);                              \
    bf16x8 a10 = LF(LA, wm + (2*(Q)+1)*16 + lr, hi16);                                 \
    bf16x8 a11 = LF(LA, wm + (2*(Q)+1)*16 + lr, 64 + hi16);                            \
    bf16x8 b00 = LF(LB, wn +  0 + lr, hi16), b01 = LF(LB, wn +  0 + lr, 64 + hi16);    \
    bf16x8 b10 = LF(LB, wn + 16 + lr, hi16), b11 = LF(LB, wn + 16 + lr, 64 + hi16);    \
    bf16x8 b20 = LF(LB, wn + 32 + lr, hi16), b21 = LF(LB, wn + 32 + lr, 64 + hi16);    \
    bf16x8 b30 = LF(LB, wn + 48 + lr, hi16), b31 = LF(LB, wn + 48 + lr, 64 + hi16);    \
    STAGES                                                                             \
    __builtin_amdgcn_s_barrier();                                                      \
    asm volatile("s_waitcnt lgkmcnt(0)" ::: "memory");                                 \
    __builtin_amdgcn_sched_barrier(0);                                                 \
    __builtin_amdgcn_s_setprio(1);                                                     \
    acc[2*(Q)][0] = MF(a00, b00, acc[2*(Q)][0]); acc[2*(Q)][0] = MF(a01, b01, acc[2*(Q)][0]); \
    acc[2*(Q)][1] = MF(a00, b10, acc[2*(Q)][1]); acc[2*(Q)][1] = MF(a01, b11, acc[2*(Q)][1]); \
    acc[2*(Q)][2] = MF(a00, b20, acc[2*(Q)][2]); acc[2*(Q)][2] = MF(a01, b21, acc[2*(Q)][2]); \
    acc[2*(Q)][3] = MF(a00, b30, acc[2*(Q)][3]); acc[2*(Q)][3] = MF(a01, b31, acc[2*(Q)][3]); \
    acc[2*(Q)+1][0] = MF(a10, b00, acc[2*(Q)+1][0]); acc[2*(Q)+1][0] = MF(a11, b01, acc[2*(Q)+1][0]); \
    acc[2*(Q)+1][1] = MF(a10, b10, acc[2*(Q)+1][1]); acc[2*(Q)+1][1] = MF(a11, b11, acc[2*(Q)+1][1]); \
    acc[2*(Q)+1][2] = MF(a10, b20, acc[2*(Q)+1][2]); acc[2*(Q)+1][2] = MF(a11, b21, acc[2*(Q)+1][2]); \
    acc[2*(Q)+1][3] = MF(a10, b30, acc[2*(Q)+1][3]); acc[2*(Q)+1][3] = MF(a11, b31, acc[2*(Q)+1][3]); \
    __builtin_amdgcn_s_setprio(0);                                                     \
    VMW                                                                                \
    __builtin_amdgcn_s_barrier();                                                      \
  }

#define VM2 asm volatile("s_waitcnt vmcnt(2)" ::: "memory"); __builtin_amdgcn_sched_barrier(0);
#define VM0 asm volatile("s_waitcnt vmcnt(0)" ::: "memory"); __builtin_amdgcn_sched_barrier(0);

// Pipeline body: fills acc[8][4]. A row stride 2048 B, B row stride 2048 B.
// K-tile kt: tap = kt>>4 (A row shift & B slab), kk-byte = (kt&15)<<7.
#define GEMM_PIPE(KT)                                                                  \
  const char* A0 = lds;            const char* B0c = lds + 32768;                      \
  const char* A1 = lds + 65536;    const char* B1c = lds + 98304;                      \
  char* A0w = lds; char* B0w = lds + 32768; char* A1w = lds + 65536; char* B1w = lds + 98304; \
  f32x4 acc[8][4] = {};                                                                \
  /* prologue: kt0 full + half of A(kt1) */                                            \
  stageC(Ab(0), A0w, 0, tid);   stageC(Ab(0), A0w, 128, tid);                          \
  stageC(Ab(0), A0w, 64, tid);  stageC(Ab(0), A0w, 192, tid);                          \
  stageC(Bb(0), B0w, 0, tid);   stageC(Bb(0), B0w, 64, tid);                           \
  stageC(Bb(0), B0w, 128, tid); stageC(Bb(0), B0w, 192, tid);                          \
  stageC(Ab(1), A1w, 0, tid);   stageC(Ab(1), A1w, 128, tid);                          \
  VM2                                                                                  \
  __builtin_amdgcn_s_barrier();                                                        \
  for (int i = 0; i < (KT)/2 - 1; ++i) {                                               \
    const int kt1 = 2*i + 1;                                                           \
    PH(0, A0, B0c,                                                                     \
       stageC(Ab(kt1), A1w, 64, tid);  stageC(Ab(kt1), A1w, 192, tid);                 \
       stageC(Bb(kt1), B1w, 0, tid);   stageC(Bb(kt1), B1w, 64, tid); , )              \
    PH(1, A0, B0c, stageC(Bb(kt1), B1w, 128, tid); stageC(Bb(kt1), B1w, 192, tid); , ) \
    PH(2, A0, B0c, stageC(Ab(kt1+1), A0w, 0, tid); stageC(Ab(kt1+1), A0w, 128, tid); , ) \
    PH(3, A0, B0c, , VM2)                                                              \
    PH(0, A1, B1c,                                                                     \
       stageC(Ab(kt1+1), A0w, 64, tid); stageC(Ab(kt1+1), A0w, 192, tid);              \
       stageC(Bb(kt1+1), B0w, 0, tid);  stageC(Bb(kt1+1), B0w, 64, tid); , )           \
    PH(1, A1, B1c, stageC(Bb(kt1+1), B0w, 128, tid); stageC(Bb(kt1+1), B0w, 192, tid); , ) \
    PH(2, A1, B1c, stageC(Ab(kt1+2), A1w, 0, tid); stageC(Ab(kt1+2), A1w, 128, tid); , ) \
    PH(3, A1, B1c, , VM2)                                                              \
  }                                                                                    \
  { /* last iteration: stage only kt1's remaining halves; drain fully at ph4 */        \
    const int kt1 = (KT) - 1;                                                          \
    PH(0, A0, B0c,                                                                     \
       stageC(Ab(kt1), A1w, 64, tid);  stageC(Ab(kt1), A1w, 192, tid);                 \
       stageC(Bb(kt1), B1w, 0, tid);   stageC(Bb(kt1), B1w, 64, tid); , )              \
    PH(1, A0, B0c, stageC(Bb(kt1), B1w, 128, tid); stageC(Bb(kt1), B1w, 192, tid); , ) \
    PH(2, A0, B0c, , )                                                                 \
    PH(3, A0, B0c, , VM0)                                                              \
    PH(0, A1, B1c, , )                                                                 \
    PH(1, A1, B1c, , )                                                                 \
    PH(2, A1, B1c, , )                                                                 \
    PH(3, A1, B1c, , )                                                                 \
  }

// ---------------- simple cast / gather kernels ----------------

__global__ void cast4(const float* __restrict__ src, u16* __restrict__ dst, int n4) {
  int i = blockIdx.x * 256 + threadIdx.x;
  if (i < n4) {
    float4 v = ((const float4*)src)[i];
    u16x4 o = { f2bf(v.x), f2bf(v.y), f2bf(v.z), f2bf(v.w) };
    ((u16x4*)dst)[i] = o;
  }
}

// cw[o][i][k] (stride W in k) -> W matrices BT_k[o][i], k-major contiguous reads
template<int W>
__global__ void cast_conv_w(const float* __restrict__ src, u16* __restrict__ dst) {
  int i = blockIdx.x * 256 + threadIdx.x;  // over 1024*1024
  if (i < 1024 * 1024) {
#pragma unroll
    for (int k = 0; k < W; ++k)
      dst[(size_t)k * (1024 * 1024) + i] = f2bf(src[(size_t)i * W + k]);
  }
}

// W12 pack: 16-row interleave of w1/w2 so a 256-wide N-tile holds matched pairs
__global__ void pack_w12(const float* __restrict__ w1, const float* __restrict__ w2,
                         u16* __restrict__ W12) {
  int i = blockIdx.x * 256 + threadIdx.x;  // over 2048*1024
  if (i < 2048 * 1024) {
    int n2 = i >> 10, k = i & 1023;
    int j = n2 >> 4, m = n2 & 15;
    const float* src = (j & 1) ? w2 : w1;
    W12[i] = f2bf(src[(size_t)((j >> 1) * 16 + m) * 1024 + k]);
  }
}

__global__ void gather_cast(const int* __restrict__ dq, const int* __restrict__ das,
                            const float* __restrict__ emb, u16* __restrict__ X) {
  const int row = blockIdx.x;        // [0, M_PAD)
  const int c   = threadIdx.x;       // 256 threads * 4 floats = 1024
  size_t dsto = (size_t)row * DIM + c * 4;
  if (row >= M_ALL) {                // zero pad rows so GEMM tiles are clean
    u16x4 z = {0, 0, 0, 0};
    *(u16x4*)(X + dsto) = z;
    return;
  }
  const int tok = (row < T_ANS) ? das[row] : dq[row - T_ANS];
  float4 v = ((const float4*)(emb + (size_t)tok * DIM))[c];
  u16x4 o = { f2bf(v.x), f2bf(v.y), f2bf(v.z), f2bf(v.w) };
  *(u16x4*)(X + dsto) = o;
}

__global__ void transpose_pq(const u16* __restrict__ pa, u16* __restrict__ pqT) {
  int i = blockIdx.x * 256 + threadIdx.x;  // 1024*64
  int e = i >> 6, q = i & 63;
  pqT[i] = pa[(size_t)(T_ANS + q) * DIM + e];
}

__global__ void zero_pad_sim(u16* __restrict__ sim) {
  int i = blockIdx.x * 256 + threadIdx.x;
  if (i < 2 * DIM) sim[(size_t)T_ANS * DIM + i] = 0;
}

__global__ void cast_cat(const float* __restrict__ cat, u16* __restrict__ catb) {
  int i = blockIdx.x * 256 + threadIdx.x;  // 128*3072
  if (i < 128 * 3072) {
    int row = i / 3072;
    catb[i] = (row < 64) ? f2bf(cat[i]) : (u16)0;
  }
}

// ---------------- projection (8-phase): pa = sig(X@w1^T+b1)*tanh(X@w2^T+b2) --------
// One GEMM M=33024, N=2048 (interleaved W12), K=1024 (KT=16).

__global__ __launch_bounds__(512, 1)
void proj_g(const u16* __restrict__ X, const u16* __restrict__ W12,
            const float* __restrict__ b1, const float* __restrict__ b2,
            u16* __restrict__ pa) {
  extern __shared__ char lds[];
  const int tid = threadIdx.x, lane = tid & 63;
  const int wid = tid >> 6;
  const int wm = (wid >> 2) * 128, wn = (wid & 3) * 64;
  const int lr = lane & 15, hi16 = (lane >> 4) * 16;
  const int tm = blockIdx.x * 256, tn = blockIdx.y * 256;
  const char* Ag = (const char*)X + (size_t)tm * 2048;
  const char* Bg = (const char*)W12 + (size_t)tn * 2048;
  auto Ab = [&](int kt) { return Ag + (kt >> 4) * 2048 + ((kt & 15) << 7); };
  auto Bb = [&](int kt) { return Bg + (size_t)(kt >> 4) * 2097152 + ((kt & 15) << 7); };

  GEMM_PIPE(16)

  const int lg = (lane >> 4) * 4;
#pragma unroll
  for (int pp = 0; pp < 2; ++pp) {
    const int col = (tn >> 1) + ((wn >> 5) + pp) * 16 + lr;
    const float b1v = b1[col], b2v = b2[col];
#pragma unroll
    for (int mi = 0; mi < 8; ++mi)
#pragma unroll
      for (int r = 0; r < 4; ++r) {
        const int row = tm + wm + mi * 16 + lg + r;
        const float x1 = acc[mi][2 * pp][r] + b1v;
        const float x2 = acc[mi][2 * pp + 1][r] + b2v;
        const float sg = 1.f / (1.f + __expf(-x1));
        const float th = 2.f / (1.f + __expf(-2.f * x2)) - 1.f;
        pa[(size_t)row * DIM + col] = f2bf(sg * th);
      }
  }
}

// ---------------- conv (window W, 8-phase) + relu + per-answer DMax ----------------
// GEMM M=32768, N=1024, K=W*1024; tap = k/1024 shifts A rows & selects B slab.

template<int W>
__global__ __launch_bounds__(512, 1)
void conv_g(const u16* __restrict__ sim, const u16* __restrict__ Bw,
            const float* __restrict__ cb, float* __restrict__ cat) {
  extern __shared__ char lds[];
  const int tid = threadIdx.x, lane = tid & 63;
  const int wid = tid >> 6;
  const int wm = (wid >> 2) * 128, wn = (wid & 3) * 64;
  const int lr = lane & 15, hi16 = (lane >> 4) * 16;
  const int tm = blockIdx.x * 256, tn = blockIdx.y * 256;
  const char* Ag = (const char*)sim + (size_t)tm * 2048;
  const char* Bg = (const char*)Bw + (size_t)tn * 2048;
  auto Ab = [&](int kt) { return Ag + (kt >> 4) * 2048 + ((kt & 15) << 7); };
  auto Bb = [&](int kt) { return Bg + (size_t)(kt >> 4) * 2097152 + ((kt & 15) << 7); };

  GEMM_PIPE(16 * W)

  // epilogue: +cb, relu, mask boundary rows, column max, atomicMax into cat
  const int lg = (lane >> 4) * 4;
  const int n = tm >> 9;  // 256 | 512 so one answer per tile
#pragma unroll
  for (int ni = 0; ni < 4; ++ni) {
    const int col = tn + wn + ni * 16 + lr;
    const float cbv = cb[col];
    float vmax = 0.f;
#pragma unroll
    for (int mi = 0; mi < 8; ++mi)
#pragma unroll
      for (int r = 0; r < 4; ++r) {
        const int t = tm + wm + mi * 16 + lg + r;
        float v = fmaxf(acc[mi][ni][r] + cbv, 0.f);
        if ((t & 511) > 512 - W) v = 0.f;  // window straddles answer boundary
        vmax = fmaxf(vmax, v);
      }
    vmax = fmaxf(vmax, __shfl_xor(vmax, 16));
    vmax = fmaxf(vmax, __shfl_xor(vmax, 32));
    if (lane < 16)
      atomicMax((int*)&cat[(size_t)n * 3072 + (W - 1) * 1024 + col], __float_as_int(vmax));
  }
}

// ---------------- attention S = pa @ pq^T  (split-K x4, deterministic partials) ----

__global__ __launch_bounds__(256, 2)
void attn_s(const u16* __restrict__ pa, float* __restrict__ Spart) {
  __shared__ alignas(16) u16 sA[128 * 32];
  __shared__ alignas(16) u16 sB[64 * 32];
  const int tid = threadIdx.x, lane = tid & 63;
  const int tm = blockIdx.x * 128;
  const int kbase = blockIdx.y * 256;     // K chunk of 256
  const int wid = tid >> 6;
  const int wm = (wid >> 1) * 64, wn = (wid & 1) * 32;
  const u16* pq = pa + (size_t)T_ANS * DIM;
  f32x4 acc[4][2] = {};
  for (int k0 = kbase; k0 < kbase + 256; k0 += 32) {
#pragma unroll
    for (int j = 0; j < 2; ++j) {
      const int f = tid * 16 + j * 4096;
      const int r = f >> 6, cb = f & 63;
      gl2lds16((const char*)pa + (size_t)(tm + r) * 2048 + k0 * 2 + cb, (char*)sA + f);
    }
    {
      const int f = tid * 16;  // 4 KB, single issue
      const int r = f >> 6, cb = f & 63;
      gl2lds16((const char*)pq + (size_t)r * 2048 + k0 * 2 + cb, (char*)sB + f);
    }
    __syncthreads();
    const int lr = lane & 15, lk = (lane >> 4) * 8;
    bf16x8 af[4], bfr[2];
#pragma unroll
    for (int i = 0; i < 4; ++i)
      af[i] = *(const bf16x8*)(sA + (wm + i * 16 + lr) * 32 + lk);
#pragma unroll
    for (int i = 0; i < 2; ++i)
      bfr[i] = *(const bf16x8*)(sB + (wn + i * 16 + lr) * 32 + lk);
#pragma unroll
    for (int mi = 0; mi < 4; ++mi)
#pragma unroll
      for (int ni = 0; ni < 2; ++ni)
        acc[mi][ni] = MF(af[mi], bfr[ni], acc[mi][ni]);
    __syncthreads();
  }
  const int lr = lane & 15, lg = (lane >> 4) * 4;
  float* Sp = Spart + (size_t)blockIdx.y * (T_ANS * 64);
#pragma unroll
  for (int mi = 0; mi < 4; ++mi)
#pragma unroll
    for (int ni = 0; ni < 2; ++ni)
#pragma unroll
      for (int r = 0; r < 4; ++r) {
        const int row = tm + wm + mi * 16 + lg + r;
        const int col = wn + ni * 16 + lr;
        Sp[(size_t)row * 64 + col] = acc[mi][ni][r];
      }
}

__global__ void softmax64(const float* __restrict__ Spart, u16* __restrict__ alpha) {
  const int row = blockIdx.x * 4 + (threadIdx.x >> 6);
  const int lane = threadIdx.x & 63;
  const size_t o = (size_t)row * 64 + lane;
  float v = Spart[o] + Spart[(size_t)1 * T_ANS * 64 + o]
          + Spart[(size_t)2 * T_ANS * 64 + o] + Spart[(size_t)3 * T_ANS * 64 + o];
  float m = v;
#pragma unroll
  for (int o2 = 32; o2 > 0; o2 >>= 1) m = fmaxf(m, __shfl_xor(m, o2));
  const float e = __expf(v - m);
  float s = e;
#pragma unroll
  for (int o2 = 32; o2 > 0; o2 >>= 1) s += __shfl_xor(s, o2);
  alpha[(size_t)row * 64 + lane] = f2bf(e / s);
}

// ---------------- Y = alpha @ pq ; sim = pa * Y ----------------

__global__ __launch_bounds__(256, 2)
void attn_y_sim(const u16* __restrict__ alpha, const u16* __restrict__ pqT,
                const u16* __restrict__ pa, u16* __restrict__ sim) {
  __shared__ alignas(16) u16 sA[128 * 32];
  __shared__ alignas(16) u16 sB[128 * 32];
  const int tid = threadIdx.x, lane = tid & 63;
  const int tm = blockIdx.x * 128, tn = blockIdx.y * 128;
  const int wid = tid >> 6;
  const int wm = (wid >> 1) * 64, wn = (wid & 1) * 64;
  f32x4 acc[4][4] = {};
  for (int k0 = 0; k0 < 64; k0 += 32) {
#pragma unroll
    for (int j = 0; j < 2; ++j) {
      const int f = tid * 16 + j * 4096;
      const int r = f >> 6, cb = f & 63;
      gl2lds16((const char*)alpha + (size_t)(tm + r) * 128 + k0 * 2 + cb, (char*)sA + f);
      gl2lds16((const char*)pqT   + (size_t)(tn + r) * 128 + k0 * 2 + cb, (char*)sB + f);
    }
    __syncthreads();
    const int lr = lane & 15, lk = (lane >> 4) * 8;
    bf16x8 af[4], bfr[4];
#pragma unroll
    for (int i = 0; i < 4; ++i) {
      af[i]  = *(const bf16x8*)(sA + (wm + i * 16 + lr) * 32 + lk);
      bfr[i] = *(const bf16x8*)(sB + (wn + i * 16 + lr) * 32 + lk);
    }
#pragma unroll
    for (int mi = 0; mi < 4; ++mi)
#pragma unroll
      for (int ni = 0; ni < 4; ++ni)
        acc[mi][ni] = MF(af[mi], bfr[ni], acc[mi][ni]);
    __syncthreads();
  }
  const int lr = lane & 15, lg = (lane >> 4) * 4;
#pragma unroll
  for (int ni = 0; ni < 4; ++ni) {
    const int col = tn + wn + ni * 16 + lr;
#pragma unroll
    for (int mi = 0; mi < 4; ++mi)
#pragma unroll
      for (int r = 0; r < 4; ++r) {
        const int row = tm + wm + mi * 16 + lg + r;
        const size_t o = (size_t)row * DIM + col;
        sim[o] = f2bf(bf2f(pa[o]) * acc[mi][ni][r]);
      }
  }
}

// ---------------- final: h = tanh(cat @ lin^T + b) ----------------

__global__ __launch_bounds__(256, 2)
void final_h(const u16* __restrict__ catb, const u16* __restrict__ linb,
             const float* __restrict__ lin_b, float* __restrict__ h) {
  __shared__ alignas(16) u16 sA[128 * 32];
  __shared__ alignas(16) u16 sB[128 * 32];
  const int tid = threadIdx.x, lane = tid & 63;
  const int tn = blockIdx.y * 128;
  const int wid = tid >> 6;
  const int wm = (wid >> 1) * 64, wn = (wid & 1) * 64;
  f32x4 acc[4][4] = {};
  for (int k0 = 0; k0 < 3072; k0 += 32) {
#pragma unroll
    for (int j = 0; j < 2; ++j) {
      const int f = tid * 16 + j * 4096;
      const int r = f >> 6, cb = f & 63;
      gl2lds16((const char*)catb + (size_t)r * 6144 + k0 * 2 + cb, (char*)sA + f);
      gl2lds16((const char*)linb + (size_t)(tn + r) * 6144 + k0 * 2 + cb, (char*)sB + f);
    }
    __syncthreads();
    const int lr = lane & 15, lk = (lane >> 4) * 8;
    bf16x8 af[4], bfr[4];
#pragma unroll
    for (int i = 0; i < 4; ++i) {
      af[i]  = *(const bf16x8*)(sA + (wm + i * 16 + lr) * 32 + lk);
      bfr[i] = *(const bf16x8*)(sB + (wn + i * 16 + lr) * 32 + lk);
    }
#pragma unroll
    for (int mi = 0; mi < 4; ++mi)
#pragma unroll
      for (int ni = 0; ni < 4; ++ni)
        acc[mi][ni] = MF(af[mi], bfr[ni], acc[mi][ni]);
    __syncthreads();
  }
  const int lr = lane & 15, lg = (lane >> 4) * 4;
#pragma unroll
  for (int ni = 0; ni < 4; ++ni) {
    const int col = tn + wn + ni * 16 + lr;
    const float bv = lin_b[col];
#pragma unroll
    for (int mi = 0; mi < 4; ++mi)
#pragma unroll
      for (int r = 0; r < 4; ++r) {
        const int row = wm + mi * 16 + lg + r;
        if (row < 64) {
          const float x = acc[mi][ni][r] + bv;
          h[(size_t)row * DIM + col] = 2.f / (1.f + __expf(-2.f * x)) - 1.f;
        }
      }
  }
}

__global__ void final_logits(const float* __restrict__ h, const float* __restrict__ soft_w,
                             const float* __restrict__ soft_b, float* __restrict__ out) {
  __shared__ float part[256];
  const int t = threadIdx.x;
  const int n = t >> 2, q = t & 3;
  float s = 0.f;
  for (int j = q * 256; j < q * 256 + 256; ++j) s += h[(size_t)n * DIM + j] * soft_w[j];
  part[t] = s;
  __syncthreads();
  if (t < 64) {
    float logit = part[t * 4] + part[t * 4 + 1] + part[t * 4 + 2] + part[t * 4 + 3] + soft_b[0];
    float m = logit;
#pragma unroll
    for (int o = 32; o > 0; o >>= 1) m = fmaxf(m, __shfl_xor(m, o));
    float e = __expf(logit - m);
    float ssum = e;
#pragma unroll
    for (int o = 32; o > 0; o >>= 1) ssum += __shfl_xor(ssum, o);
    out[t] = (logit - m) - logf(ssum);
  }
}

// ---------------- launcher ----------------

extern "C" void kernel_launch(void* const* d_in, const int* in_sizes, int n_in,
                              void* d_out, int out_size, void* d_ws, size_t ws_size,
                              hipStream_t stream) {
  const int*   data_q  = (const int*)d_in[0];
  const int*   data_as = (const int*)d_in[1];
  const float* emb     = (const float*)d_in[2];
  const float* w1      = (const float*)d_in[3];
  const float* b1      = (const float*)d_in[4];
  const float* w2      = (const float*)d_in[5];
  const float* b2      = (const float*)d_in[6];
  const float* cw1     = (const float*)d_in[7];
  const float* cb1     = (const float*)d_in[8];
  const float* cw2     = (const float*)d_in[9];
  const float* cb2     = (const float*)d_in[10];
  const float* cw3     = (const float*)d_in[11];
  const float* cb3     = (const float*)d_in[12];
  const float* lin_w   = (const float*)d_in[13];
  const float* lin_b   = (const float*)d_in[14];
  const float* soft_w  = (const float*)d_in[15];
  const float* soft_b  = (const float*)d_in[16];
  float* out = (float*)d_out;

  // allow 128 KiB dynamic LDS on the pipelined kernels (host attr set, capture-safe)
  hipFuncSetAttribute((const void*)proj_g, hipFuncAttributeMaxDynamicSharedMemorySize, 131072);
  hipFuncSetAttribute((const void*)conv_g<1>, hipFuncAttributeMaxDynamicSharedMemorySize, 131072);
  hipFuncSetAttribute((const void*)conv_g<2>, hipFuncAttributeMaxDynamicSharedMemorySize, 131072);
  hipFuncSetAttribute((const void*)conv_g<3>, hipFuncAttributeMaxDynamicSharedMemorySize, 131072);

  // workspace layout (~167 MB total)
  u16* X     = (u16*)d_ws;                         // [M_PAD][1024] bf16; reused: Spart, then sim
  u16* pa    = X    + (size_t)M_PAD * DIM;         // [M_PAD][1024] bf16 (rows T..T+63 = pq)
  u16* W12   = pa   + (size_t)M_PAD * DIM;         // [2048][1024] interleaved w1/w2
  u16* cwb   = W12  + (size_t)2 * 1024 * 1024;     // 6 x [1024][1024]
  u16* linb  = cwb  + (size_t)6 * 1024 * 1024;     // [1024][3072]
  u16* pqT   = linb + (size_t)3 * 1024 * 1024;     // [1024][64]
  u16* alpha = pqT  + 64 * 1024;                   // [T][64] bf16
  float* cat = (float*)(alpha + (size_t)T_ANS * 64);  // [64][3072] f32 pools
  u16* catb  = (u16*)(cat + 64 * 3072);            // [128][3072] bf16 (rows 64+ zero)
  float* h   = (float*)(catb + 128 * 3072);        // [64][1024] f32
  u16* simb  = X;                                  // alias: [T+2][1024] bf16
  float* Spart = (float*)X;                        // alias: [4][T][64] f32 (33.6 MB < 67 MB)

  hipMemsetAsync(cat, 0, 64 * 3072 * sizeof(float), stream);

  pack_w12<<<8192, 256, 0, stream>>>(w1, w2, W12);
  cast4<<<3072, 256, 0, stream>>>(lin_w, linb, 3072 * 1024 / 4);
  cast_conv_w<1><<<4096, 256, 0, stream>>>(cw1, cwb);
  cast_conv_w<2><<<4096, 256, 0, stream>>>(cw2, cwb + (size_t)1 * 1024 * 1024);
  cast_conv_w<3><<<4096, 256, 0, stream>>>(cw3, cwb + (size_t)3 * 1024 * 1024);

  gather_cast<<<M_PAD, 256, 0, stream>>>(data_q, data_as, emb, X);

  proj_g<<<dim3(M_PAD / 256, 8), 512, 131072, stream>>>(X, W12, b1, b2, pa);
  transpose_pq<<<256, 256, 0, stream>>>(pa, pqT);

  attn_s<<<dim3(T_ANS / 128, 4), 256, 0, stream>>>(pa, Spart);
  softmax64<<<T_ANS / 4, 256, 0, stream>>>(Spart, alpha);
  attn_y_sim<<<dim3(T_ANS / 128, 8), 256, 0, stream>>>(alpha, pqT, pa, simb);
  zero_pad_sim<<<8, 256, 0, stream>>>(simb);

  conv_g<1><<<dim3(T_ANS / 256, 4), 512, 131072, stream>>>(simb, cwb, cb1, cat);
  conv_g<2><<<dim3(T_ANS / 256, 4), 512, 131072, stream>>>(simb, cwb + (size_t)1 * 1024 * 1024, cb2, cat);
  conv_g<3><<<dim3(T_ANS / 256, 4), 512, 131072, stream>>>(simb, cwb + (size_t)3 * 1024 * 1024, cb3, cat);

  cast_cat<<<1536, 256, 0, stream>>>(cat, catb);
  final_h<<<dim3(1, 8), 256, 0, stream>>>(catb, linb, lin_b, h);
  final_logits<<<1, 256, 0, stream>>>(h, soft_w, soft_b, out);
}

// Round 5
// 786.180 us; speedup vs baseline: 1.1839x; 1.1839x over previous
//
#include <hip/hip_runtime.h>

#define DEV __device__ __forceinline__

typedef __bf16 bf16x8 __attribute__((ext_vector_type(8)));
typedef float f32x4 __attribute__((ext_vector_type(4)));
typedef unsigned short u16;
typedef u16 u16x4 __attribute__((ext_vector_type(4)));

constexpr int T_ANS = 32768;        // N*La answer tokens
constexpr int LQ    = 64;
constexpr int M_ALL = T_ANS + LQ;   // 32832 rows fed to projection
constexpr int M_PAD = 33024;        // 129*256 (256-tile padded)
constexpr int DIM   = 1024;

DEV u16 f2bf(float x) {
  unsigned u = __float_as_uint(x);
  return (u16)((u + 0x7FFFu + ((u >> 16) & 1u)) >> 16);
}
DEV float bf2f(u16 s) { return __uint_as_float(((unsigned)s) << 16); }

DEV void gl2lds16(const void* g, void* l) {
  __builtin_amdgcn_global_load_lds(
      (const __attribute__((address_space(1))) unsigned int*)g,
      (__attribute__((address_space(3))) unsigned int*)l, 16, 0, 0);
}

#define MF(A, B, C) __builtin_amdgcn_mfma_f32_16x16x32_bf16(A, B, C, 0, 0, 0)

// ---------------- 8-phase 256x256 GEMM core ----------------
// LDS: [A0 32K][B0 32K][A1 32K][B1 32K]. Rows 128 B, swizzle byte ^= ((row&7)<<4).
// gl2lds dest LINEAR; global source col-block inverse-XOR'd (rule 21).
// Per K-tile group (4 phases): B-frags loaded ONCE (phase 0, 8 ds_read) and held in
// regs; phases 1-3 load 4 A-frags each  ->  24 b128/wave/K-tile (was 48: B x4 reload).

DEV void stageC(const char* gk, char* ldsT, int row0, int tid) {
  const int f = tid << 4;                 // 0..8191, 64 rows per chunk
  const int r = row0 + (f >> 7);
  const int cb = ((f >> 4) & 7) ^ (r & 7);
  gl2lds16(gk + (size_t)r * 2048 + (cb << 4), ldsT + (row0 << 7) + f);
}

DEV bf16x8 LF(const char* ldsT, int row, int cbyte) {
  return *(const bf16x8*)(ldsT + (row << 7) + (cbyte ^ ((row & 7) << 4)));
}

#define MQUAD(Q, a00, a01, a10, a11)                                                  \
    acc[2*(Q)][0] = MF(a00, bb00, acc[2*(Q)][0]); acc[2*(Q)][0] = MF(a01, bb01, acc[2*(Q)][0]); \
    acc[2*(Q)][1] = MF(a00, bb10, acc[2*(Q)][1]); acc[2*(Q)][1] = MF(a01, bb11, acc[2*(Q)][1]); \
    acc[2*(Q)][2] = MF(a00, bb20, acc[2*(Q)][2]); acc[2*(Q)][2] = MF(a01, bb21, acc[2*(Q)][2]); \
    acc[2*(Q)][3] = MF(a00, bb30, acc[2*(Q)][3]); acc[2*(Q)][3] = MF(a01, bb31, acc[2*(Q)][3]); \
    acc[2*(Q)+1][0] = MF(a10, bb00, acc[2*(Q)+1][0]); acc[2*(Q)+1][0] = MF(a11, bb01, acc[2*(Q)+1][0]); \
    acc[2*(Q)+1][1] = MF(a10, bb10, acc[2*(Q)+1][1]); acc[2*(Q)+1][1] = MF(a11, bb11, acc[2*(Q)+1][1]); \
    acc[2*(Q)+1][2] = MF(a10, bb20, acc[2*(Q)+1][2]); acc[2*(Q)+1][2] = MF(a11, bb21, acc[2*(Q)+1][2]); \
    acc[2*(Q)+1][3] = MF(a10, bb30, acc[2*(Q)+1][3]); acc[2*(Q)+1][3] = MF(a11, bb31, acc[2*(Q)+1][3]);

// Phase 0 of a K-tile group: load all B (8) + A m0,m1 (4); MFMA quadrant 0.
#define PHB(LA, LB, STAGES, VMW)                                                      \
  {                                                                                   \
    bb00 = LF(LB, wn +  0 + lr, hi16); bb01 = LF(LB, wn +  0 + lr, 64 + hi16);        \
    bb10 = LF(LB, wn + 16 + lr, hi16); bb11 = LF(LB, wn + 16 + lr, 64 + hi16);        \
    bb20 = LF(LB, wn + 32 + lr, hi16); bb21 = LF(LB, wn + 32 + lr, 64 + hi16);        \
    bb30 = LF(LB, wn + 48 + lr, hi16); bb31 = LF(LB, wn + 48 + lr, 64 + hi16);        \
    bf16x8 a00 = LF(LA, wm + lr, hi16),      a01 = LF(LA, wm + lr, 64 + hi16);        \
    bf16x8 a10 = LF(LA, wm + 16 + lr, hi16), a11 = LF(LA, wm + 16 + lr, 64 + hi16);   \
    STAGES                                                                            \
    __builtin_amdgcn_s_barrier();                                                     \
    asm volatile("s_waitcnt lgkmcnt(0)" ::: "memory");                                \
    __builtin_amdgcn_sched_barrier(0);                                                \
    __builtin_amdgcn_s_setprio(1);                                                    \
    MQUAD(0, a00, a01, a10, a11)                                                      \
    __builtin_amdgcn_s_setprio(0);                                                    \
    VMW                                                                               \
    __builtin_amdgcn_s_barrier();                                                     \
  }

// Phases 1-3: load A m(2Q),m(2Q+1) only; MFMA quadrant Q with resident B.
#define PHA(Q, LA, STAGES, VMW)                                                       \
  {                                                                                   \
    bf16x8 a00 = LF(LA, wm + (2*(Q))*16 + lr, hi16);                                  \
    bf16x8 a01 = LF(LA, wm + (2*(Q))*16 + lr, 64 + hi16);                             \
    bf16x8 a10 = LF(LA, wm + (2*(Q)+1)*16 + lr, hi16);                                \
    bf16x8 a11 = LF(LA, wm + (2*(Q)+1)*16 + lr, 64 + hi16);                           \
    STAGES                                                                            \
    __builtin_amdgcn_s_barrier();                                                     \
    asm volatile("s_waitcnt lgkmcnt(0)" ::: "memory");                                \
    __builtin_amdgcn_sched_barrier(0);                                                \
    __builtin_amdgcn_s_setprio(1);                                                    \
    MQUAD(Q, a00, a01, a10, a11)                                                      \
    __builtin_amdgcn_s_setprio(0);                                                    \
    VMW                                                                               \
    __builtin_amdgcn_s_barrier();                                                     \
  }

#define VM2 asm volatile("s_waitcnt vmcnt(2)" ::: "memory"); __builtin_amdgcn_sched_barrier(0);
#define VM0 asm volatile("s_waitcnt vmcnt(0)" ::: "memory"); __builtin_amdgcn_sched_barrier(0);

#define GROUP(LA, LB, S1, S2, S3, VMW)                                                \
  PHB(LA, LB, S1, )                                                                   \
  PHA(1, LA, S2, )                                                                    \
  PHA(2, LA, S3, )                                                                    \
  PHA(3, LA, , VMW)

// Stage placement identical to the verified R4 schedule; only read/MFMA grouping changed.
#define GEMM_PIPE(KT)                                                                 \
  const char* A0 = lds;            const char* B0c = lds + 32768;                     \
  const char* A1 = lds + 65536;    const char* B1c = lds + 98304;                     \
  char* A0w = lds; char* B0w = lds + 32768; char* A1w = lds + 65536; char* B1w = lds + 98304; \
  f32x4 acc[8][4] = {};                                                               \
  bf16x8 bb00, bb01, bb10, bb11, bb20, bb21, bb30, bb31;                              \
  stageC(Ab(0), A0w, 0, tid);   stageC(Ab(0), A0w, 128, tid);                         \
  stageC(Ab(0), A0w, 64, tid);  stageC(Ab(0), A0w, 192, tid);                         \
  stageC(Bb(0), B0w, 0, tid);   stageC(Bb(0), B0w, 64, tid);                          \
  stageC(Bb(0), B0w, 128, tid); stageC(Bb(0), B0w, 192, tid);                         \
  stageC(Ab(1), A1w, 0, tid);   stageC(Ab(1), A1w, 128, tid);                         \
  VM2                                                                                 \
  __builtin_amdgcn_s_barrier();                                                       \
  for (int i = 0; i < (KT)/2 - 1; ++i) {                                              \
    const int kt1 = 2*i + 1;                                                          \
    GROUP(A0, B0c,                                                                    \
      stageC(Ab(kt1), A1w, 64, tid);  stageC(Ab(kt1), A1w, 192, tid);                 \
      stageC(Bb(kt1), B1w, 0, tid);   stageC(Bb(kt1), B1w, 64, tid); ,                \
      stageC(Bb(kt1), B1w, 128, tid); stageC(Bb(kt1), B1w, 192, tid); ,               \
      stageC(Ab(kt1+1), A0w, 0, tid); stageC(Ab(kt1+1), A0w, 128, tid); ,             \
      VM2)                                                                            \
    GROUP(A1, B1c,                                                                    \
      stageC(Ab(kt1+1), A0w, 64, tid); stageC(Ab(kt1+1), A0w, 192, tid);              \
      stageC(Bb(kt1+1), B0w, 0, tid);  stageC(Bb(kt1+1), B0w, 64, tid); ,             \
      stageC(Bb(kt1+1), B0w, 128, tid); stageC(Bb(kt1+1), B0w, 192, tid); ,           \
      stageC(Ab(kt1+2), A1w, 0, tid); stageC(Ab(kt1+2), A1w, 128, tid); ,             \
      VM2)                                                                            \
  }                                                                                   \
  {                                                                                   \
    const int kt1 = (KT) - 1;                                                         \
    GROUP(A0, B0c,                                                                    \
      stageC(Ab(kt1), A1w, 64, tid);  stageC(Ab(kt1), A1w, 192, tid);                 \
      stageC(Bb(kt1), B1w, 0, tid);   stageC(Bb(kt1), B1w, 64, tid); ,                \
      stageC(Bb(kt1), B1w, 128, tid); stageC(Bb(kt1), B1w, 192, tid); ,               \
      ,                                                                               \
      VM0)                                                                            \
    GROUP(A1, B1c, , , , )                                                            \
  }

// ---------------- simple cast / gather kernels ----------------

__global__ void cast4(const float* __restrict__ src, u16* __restrict__ dst, int n4) {
  int i = blockIdx.x * 256 + threadIdx.x;
  if (i < n4) {
    float4 v = ((const float4*)src)[i];
    u16x4 o = { f2bf(v.x), f2bf(v.y), f2bf(v.z), f2bf(v.w) };
    ((u16x4*)dst)[i] = o;
  }
}

// cw[o][i][k] (stride W in k) -> W matrices BT_k[o][i], k-major contiguous reads
template<int W>
__global__ void cast_conv_w(const float* __restrict__ src, u16* __restrict__ dst) {
  int i = blockIdx.x * 256 + threadIdx.x;  // over 1024*1024
  if (i < 1024 * 1024) {
#pragma unroll
    for (int k = 0; k < W; ++k)
      dst[(size_t)k * (1024 * 1024) + i] = f2bf(src[(size_t)i * W + k]);
  }
}

// W12 pack: 16-row interleave of w1/w2 so a 256-wide N-tile holds matched pairs
__global__ void pack_w12(const float* __restrict__ w1, const float* __restrict__ w2,
                         u16* __restrict__ W12) {
  int i = blockIdx.x * 256 + threadIdx.x;  // over 2048*1024
  if (i < 2048 * 1024) {
    int n2 = i >> 10, k = i & 1023;
    int j = n2 >> 4, m = n2 & 15;
    const float* src = (j & 1) ? w2 : w1;
    W12[i] = f2bf(src[(size_t)((j >> 1) * 16 + m) * 1024 + k]);
  }
}

__global__ void gather_cast(const int* __restrict__ dq, const int* __restrict__ das,
                            const float* __restrict__ emb, u16* __restrict__ X) {
  const int row = blockIdx.x;        // [0, M_PAD)
  const int c   = threadIdx.x;       // 256 threads * 4 floats = 1024
  size_t dsto = (size_t)row * DIM + c * 4;
  if (row >= M_ALL) {                // zero pad rows so GEMM tiles are clean
    u16x4 z = {0, 0, 0, 0};
    *(u16x4*)(X + dsto) = z;
    return;
  }
  const int tok = (row < T_ANS) ? das[row] : dq[row - T_ANS];
  float4 v = ((const float4*)(emb + (size_t)tok * DIM))[c];
  u16x4 o = { f2bf(v.x), f2bf(v.y), f2bf(v.z), f2bf(v.w) };
  *(u16x4*)(X + dsto) = o;
}

__global__ void transpose_pq(const u16* __restrict__ pa, u16* __restrict__ pqT) {
  int i = blockIdx.x * 256 + threadIdx.x;  // 1024*64
  int e = i >> 6, q = i & 63;
  pqT[i] = pa[(size_t)(T_ANS + q) * DIM + e];
}

__global__ void zero_pad_sim(u16* __restrict__ sim) {
  int i = blockIdx.x * 256 + threadIdx.x;
  if (i < 2 * DIM) sim[(size_t)T_ANS * DIM + i] = 0;
}

__global__ void cast_cat(const float* __restrict__ cat, u16* __restrict__ catb) {
  int i = blockIdx.x * 256 + threadIdx.x;  // 128*3072
  if (i < 128 * 3072) {
    int row = i / 3072;
    catb[i] = (row < 64) ? f2bf(cat[i]) : (u16)0;
  }
}

// ---------------- projection (8-phase): pa = sig(X@w1^T+b1)*tanh(X@w2^T+b2) --------
// One GEMM M=33024, N=2048 (interleaved W12), K=1024 (KT=16). 1D grid 1032, XCD-swizzled.

__global__ __launch_bounds__(512, 1)
void proj_g(const u16* __restrict__ X, const u16* __restrict__ W12,
            const float* __restrict__ b1, const float* __restrict__ b2,
            u16* __restrict__ pa) {
  extern __shared__ char lds[];
  const int tid = threadIdx.x, lane = tid & 63;
  const int wid = tid >> 6;
  const int wm = (wid >> 2) * 128, wn = (wid & 3) * 64;
  const int lr = lane & 15, hi16 = (lane >> 4) * 16;
  // bijective XCD swizzle: 1032 = 8*129; same-A blocks (all 8 tn) contiguous per XCD
  const int wg = ((int)blockIdx.x % 8) * 129 + (int)blockIdx.x / 8;
  const int tm = (wg >> 3) * 256, tn = (wg & 7) * 256;
  const char* Ag = (const char*)X + (size_t)tm * 2048;
  const char* Bg = (const char*)W12 + (size_t)tn * 2048;
  auto Ab = [&](int kt) { return Ag + (kt >> 4) * 2048 + ((kt & 15) << 7); };
  auto Bb = [&](int kt) { return Bg + (size_t)(kt >> 4) * 2097152 + ((kt & 15) << 7); };

  GEMM_PIPE(16)

  // epilogue: gate, then LDS bounce (stride 132 u16: 4-apart rows hit distinct bank octets)
  u16* cw = (u16*)lds;
  const int lg = (lane >> 4) * 4;
#pragma unroll
  for (int pp = 0; pp < 2; ++pp) {
    const int clocal = ((wn >> 5) + pp) * 16 + lr;   // 0..127
    const int col = (tn >> 1) + clocal;
    const float b1v = b1[col], b2v = b2[col];
#pragma unroll
    for (int mi = 0; mi < 8; ++mi)
#pragma unroll
      for (int r = 0; r < 4; ++r) {
        const int rowL = wm + mi * 16 + lg + r;
        const float x1 = acc[mi][2 * pp][r] + b1v;
        const float x2 = acc[mi][2 * pp + 1][r] + b2v;
        const float sg = 1.f / (1.f + __expf(-x1));
        const float th = 2.f / (1.f + __expf(-2.f * x2)) - 1.f;
        cw[rowL * 132 + clocal] = f2bf(sg * th);
      }
  }
  __syncthreads();
#pragma unroll
  for (int it = 0; it < 16; ++it) {
    const int cid = it * 512 + tid;                  // 8192 chunks of 4 u16
    const int rowL = cid >> 5, c4 = (cid & 31) * 4;
    u16x4 v = *(const u16x4*)(cw + rowL * 132 + c4);
    *(u16x4*)(pa + (size_t)(tm + rowL) * DIM + (tn >> 1) + c4) = v;
  }
}

// ---------------- conv (window W, 8-phase) + relu + per-answer DMax ----------------
// GEMM M=32768, N=1024, K=W*1024; tap = k/1024 shifts A rows & selects B slab.

template<int W>
__global__ __launch_bounds__(512, 1)
void conv_g(const u16* __restrict__ sim, const u16* __restrict__ Bw,
            const float* __restrict__ cb, float* __restrict__ cat) {
  extern __shared__ char lds[];
  const int tid = threadIdx.x, lane = tid & 63;
  const int wid = tid >> 6;
  const int wm = (wid >> 2) * 128, wn = (wid & 3) * 64;
  const int lr = lane & 15, hi16 = (lane >> 4) * 16;
  // bijective XCD swizzle: 512 = 8*64; same-A blocks (all 4 tn) contiguous per XCD
  const int wg = ((int)blockIdx.x % 8) * 64 + (int)blockIdx.x / 8;
  const int tm = (wg >> 2) * 256, tn = (wg & 3) * 256;
  const char* Ag = (const char*)sim + (size_t)tm * 2048;
  const char* Bg = (const char*)Bw + (size_t)tn * 2048;
  auto Ab = [&](int kt) { return Ag + (kt >> 4) * 2048 + ((kt & 15) << 7); };
  auto Bb = [&](int kt) { return Bg + (size_t)(kt >> 4) * 2097152 + ((kt & 15) << 7); };

  GEMM_PIPE(16 * W)

  // epilogue: +cb, relu, mask boundary rows, column max, atomicMax into cat
  const int lg = (lane >> 4) * 4;
  const int n = tm >> 9;  // 256 | 512 so one answer per tile
#pragma unroll
  for (int ni = 0; ni < 4; ++ni) {
    const int col = tn + wn + ni * 16 + lr;
    const float cbv = cb[col];
    float vmax = 0.f;
#pragma unroll
    for (int mi = 0; mi < 8; ++mi)
#pragma unroll
      for (int r = 0; r < 4; ++r) {
        const int t = tm + wm + mi * 16 + lg + r;
        float v = fmaxf(acc[mi][ni][r] + cbv, 0.f);
        if ((t & 511) > 512 - W) v = 0.f;  // window straddles answer boundary
        vmax = fmaxf(vmax, v);
      }
    vmax = fmaxf(vmax, __shfl_xor(vmax, 16));
    vmax = fmaxf(vmax, __shfl_xor(vmax, 32));
    if (lane < 16)
      atomicMax((int*)&cat[(size_t)n * 3072 + (W - 1) * 1024 + col], __float_as_int(vmax));
  }
}

// ---------------- attention S = pa @ pq^T  (split-K x4, deterministic partials) ----

__global__ __launch_bounds__(256, 2)
void attn_s(const u16* __restrict__ pa, float* __restrict__ Spart) {
  __shared__ alignas(16) u16 sA[128 * 32];
  __shared__ alignas(16) u16 sB[64 * 32];
  const int tid = threadIdx.x, lane = tid & 63;
  const int tm = blockIdx.x * 128;
  const int kbase = blockIdx.y * 256;     // K chunk of 256
  const int wid = tid >> 6;
  const int wm = (wid >> 1) * 64, wn = (wid & 1) * 32;
  const u16* pq = pa + (size_t)T_ANS * DIM;
  f32x4 acc[4][2] = {};
  for (int k0 = kbase; k0 < kbase + 256; k0 += 32) {
#pragma unroll
    for (int j = 0; j < 2; ++j) {
      const int f = tid * 16 + j * 4096;
      const int r = f >> 6, cb = f & 63;
      gl2lds16((const char*)pa + (size_t)(tm + r) * 2048 + k0 * 2 + cb, (char*)sA + f);
    }
    {
      const int f = tid * 16;  // 4 KB, single issue
      const int r = f >> 6, cb = f & 63;
      gl2lds16((const char*)pq + (size_t)r * 2048 + k0 * 2 + cb, (char*)sB + f);
    }
    __syncthreads();
    const int lr = lane & 15, lk = (lane >> 4) * 8;
    bf16x8 af[4], bfr[2];
#pragma unroll
    for (int i = 0; i < 4; ++i)
      af[i] = *(const bf16x8*)(sA + (wm + i * 16 + lr) * 32 + lk);
#pragma unroll
    for (int i = 0; i < 2; ++i)
      bfr[i] = *(const bf16x8*)(sB + (wn + i * 16 + lr) * 32 + lk);
#pragma unroll
    for (int mi = 0; mi < 4; ++mi)
#pragma unroll
      for (int ni = 0; ni < 2; ++ni)
        acc[mi][ni] = MF(af[mi], bfr[ni], acc[mi][ni]);
    __syncthreads();
  }
  const int lr = lane & 15, lg = (lane >> 4) * 4;
  float* Sp = Spart + (size_t)blockIdx.y * (T_ANS * 64);
#pragma unroll
  for (int mi = 0; mi < 4; ++mi)
#pragma unroll
    for (int ni = 0; ni < 2; ++ni)
#pragma unroll
      for (int r = 0; r < 4; ++r) {
        const int row = tm + wm + mi * 16 + lg + r;
        const int col = wn + ni * 16 + lr;
        Sp[(size_t)row * 64 + col] = acc[mi][ni][r];
      }
}

__global__ void softmax64(const float* __restrict__ Spart, u16* __restrict__ alpha) {
  const int row = blockIdx.x * 4 + (threadIdx.x >> 6);
  const int lane = threadIdx.x & 63;
  const size_t o = (size_t)row * 64 + lane;
  float v = Spart[o] + Spart[(size_t)1 * T_ANS * 64 + o]
          + Spart[(size_t)2 * T_ANS * 64 + o] + Spart[(size_t)3 * T_ANS * 64 + o];
  float m = v;
#pragma unroll
  for (int o2 = 32; o2 > 0; o2 >>= 1) m = fmaxf(m, __shfl_xor(m, o2));
  const float e = __expf(v - m);
  float s = e;
#pragma unroll
  for (int o2 = 32; o2 > 0; o2 >>= 1) s += __shfl_xor(s, o2);
  alpha[(size_t)row * 64 + lane] = f2bf(e / s);
}

// ---------------- Y = alpha @ pq ; sim = pa * Y ----------------

__global__ __launch_bounds__(256, 2)
void attn_y_sim(const u16* __restrict__ alpha, const u16* __restrict__ pqT,
                const u16* __restrict__ pa, u16* __restrict__ sim) {
  __shared__ alignas(16) u16 sA[128 * 32];
  __shared__ alignas(16) u16 sB[128 * 32];
  const int tid = threadIdx.x, lane = tid & 63;
  const int tm = blockIdx.x * 128, tn = blockIdx.y * 128;
  const int wid = tid >> 6;
  const int wm = (wid >> 1) * 64, wn = (wid & 1) * 64;
  f32x4 acc[4][4] = {};
  for (int k0 = 0; k0 < 64; k0 += 32) {
#pragma unroll
    for (int j = 0; j < 2; ++j) {
      const int f = tid * 16 + j * 4096;
      const int r = f >> 6, cb = f & 63;
      gl2lds16((const char*)alpha + (size_t)(tm + r) * 128 + k0 * 2 + cb, (char*)sA + f);
      gl2lds16((const char*)pqT   + (size_t)(tn + r) * 128 + k0 * 2 + cb, (char*)sB + f);
    }
    __syncthreads();
    const int lr = lane & 15, lk = (lane >> 4) * 8;
    bf16x8 af[4], bfr[4];
#pragma unroll
    for (int i = 0; i < 4; ++i) {
      af[i]  = *(const bf16x8*)(sA + (wm + i * 16 + lr) * 32 + lk);
      bfr[i] = *(const bf16x8*)(sB + (wn + i * 16 + lr) * 32 + lk);
    }
#pragma unroll
    for (int mi = 0; mi < 4; ++mi)
#pragma unroll
      for (int ni = 0; ni < 4; ++ni)
        acc[mi][ni] = MF(af[mi], bfr[ni], acc[mi][ni]);
    __syncthreads();
  }
  const int lr = lane & 15, lg = (lane >> 4) * 4;
#pragma unroll
  for (int ni = 0; ni < 4; ++ni) {
    const int col = tn + wn + ni * 16 + lr;
#pragma unroll
    for (int mi = 0; mi < 4; ++mi)
#pragma unroll
      for (int r = 0; r < 4; ++r) {
        const int row = tm + wm + mi * 16 + lg + r;
        const size_t o = (size_t)row * DIM + col;
        sim[o] = f2bf(bf2f(pa[o]) * acc[mi][ni][r]);
      }
  }
}

// ---------------- final: h = tanh(cat @ lin^T + b) ----------------

__global__ __launch_bounds__(256, 2)
void final_h(const u16* __restrict__ catb, const u16* __restrict__ linb,
             const float* __restrict__ lin_b, float* __restrict__ h) {
  __shared__ alignas(16) u16 sA[128 * 32];
  __shared__ alignas(16) u16 sB[128 * 32];
  const int tid = threadIdx.x, lane = tid & 63;
  const int tn = blockIdx.y * 128;
  const int wid = tid >> 6;
  const int wm = (wid >> 1) * 64, wn = (wid & 1) * 64;
  f32x4 acc[4][4] = {};
  for (int k0 = 0; k0 < 3072; k0 += 32) {
#pragma unroll
    for (int j = 0; j < 2; ++j) {
      const int f = tid * 16 + j * 4096;
      const int r = f >> 6, cb = f & 63;
      gl2lds16((const char*)catb + (size_t)r * 6144 + k0 * 2 + cb, (char*)sA + f);
      gl2lds16((const char*)linb + (size_t)(tn + r) * 6144 + k0 * 2 + cb, (char*)sB + f);
    }
    __syncthreads();
    const int lr = lane & 15, lk = (lane >> 4) * 8;
    bf16x8 af[4], bfr[4];
#pragma unroll
    for (int i = 0; i < 4; ++i) {
      af[i]  = *(const bf16x8*)(sA + (wm + i * 16 + lr) * 32 + lk);
      bfr[i] = *(const bf16x8*)(sB + (wn + i * 16 + lr) * 32 + lk);
    }
#pragma unroll
    for (int mi = 0; mi < 4; ++mi)
#pragma unroll
      for (int ni = 0; ni < 4; ++ni)
        acc[mi][ni] = MF(af[mi], bfr[ni], acc[mi][ni]);
    __syncthreads();
  }
  const int lr = lane & 15, lg = (lane >> 4) * 4;
#pragma unroll
  for (int ni = 0; ni < 4; ++ni) {
    const int col = tn + wn + ni * 16 + lr;
    const float bv = lin_b[col];
#pragma unroll
    for (int mi = 0; mi < 4; ++mi)
#pragma unroll
      for (int r = 0; r < 4; ++r) {
        const int row = wm + mi * 16 + lg + r;
        if (row < 64) {
          const float x = acc[mi][ni][r] + bv;
          h[(size_t)row * DIM + col] = 2.f / (1.f + __expf(-2.f * x)) - 1.f;
        }
      }
  }
}

__global__ void final_logits(const float* __restrict__ h, const float* __restrict__ soft_w,
                             const float* __restrict__ soft_b, float* __restrict__ out) {
  __shared__ float part[256];
  const int t = threadIdx.x;
  const int n = t >> 2, q = t & 3;
  float s = 0.f;
  for (int j = q * 256; j < q * 256 + 256; ++j) s += h[(size_t)n * DIM + j] * soft_w[j];
  part[t] = s;
  __syncthreads();
  if (t < 64) {
    float logit = part[t * 4] + part[t * 4 + 1] + part[t * 4 + 2] + part[t * 4 + 3] + soft_b[0];
    float m = logit;
#pragma unroll
    for (int o = 32; o > 0; o >>= 1) m = fmaxf(m, __shfl_xor(m, o));
    float e = __expf(logit - m);
    float ssum = e;
#pragma unroll
    for (int o = 32; o > 0; o >>= 1) ssum += __shfl_xor(ssum, o);
    out[t] = (logit - m) - logf(ssum);
  }
}

// ---------------- launcher ----------------

extern "C" void kernel_launch(void* const* d_in, const int* in_sizes, int n_in,
                              void* d_out, int out_size, void* d_ws, size_t ws_size,
                              hipStream_t stream) {
  const int*   data_q  = (const int*)d_in[0];
  const int*   data_as = (const int*)d_in[1];
  const float* emb     = (const float*)d_in[2];
  const float* w1      = (const float*)d_in[3];
  const float* b1      = (const float*)d_in[4];
  const float* w2      = (const float*)d_in[5];
  const float* b2      = (const float*)d_in[6];
  const float* cw1     = (const float*)d_in[7];
  const float* cb1     = (const float*)d_in[8];
  const float* cw2     = (const float*)d_in[9];
  const float* cb2     = (const float*)d_in[10];
  const float* cw3     = (const float*)d_in[11];
  const float* cb3     = (const float*)d_in[12];
  const float* lin_w   = (const float*)d_in[13];
  const float* lin_b   = (const float*)d_in[14];
  const float* soft_w  = (const float*)d_in[15];
  const float* soft_b  = (const float*)d_in[16];
  float* out = (float*)d_out;

  // allow 128 KiB dynamic LDS on the pipelined kernels (host attr set, capture-safe)
  hipFuncSetAttribute((const void*)proj_g, hipFuncAttributeMaxDynamicSharedMemorySize, 131072);
  hipFuncSetAttribute((const void*)conv_g<1>, hipFuncAttributeMaxDynamicSharedMemorySize, 131072);
  hipFuncSetAttribute((const void*)conv_g<2>, hipFuncAttributeMaxDynamicSharedMemorySize, 131072);
  hipFuncSetAttribute((const void*)conv_g<3>, hipFuncAttributeMaxDynamicSharedMemorySize, 131072);

  // workspace layout (~167 MB total)
  u16* X     = (u16*)d_ws;                         // [M_PAD][1024] bf16; reused: Spart, then sim
  u16* pa    = X    + (size_t)M_PAD * DIM;         // [M_PAD][1024] bf16 (rows T..T+63 = pq)
  u16* W12   = pa   + (size_t)M_PAD * DIM;         // [2048][1024] interleaved w1/w2
  u16* cwb   = W12  + (size_t)2 * 1024 * 1024;     // 6 x [1024][1024]
  u16* linb  = cwb  + (size_t)6 * 1024 * 1024;     // [1024][3072]
  u16* pqT   = linb + (size_t)3 * 1024 * 1024;     // [1024][64]
  u16* alpha = pqT  + 64 * 1024;                   // [T][64] bf16
  float* cat = (float*)(alpha + (size_t)T_ANS * 64);  // [64][3072] f32 pools
  u16* catb  = (u16*)(cat + 64 * 3072);            // [128][3072] bf16 (rows 64+ zero)
  float* h   = (float*)(catb + 128 * 3072);        // [64][1024] f32
  u16* simb  = X;                                  // alias: [T+2][1024] bf16
  float* Spart = (float*)X;                        // alias: [4][T][64] f32 (33.6 MB < 67 MB)

  hipMemsetAsync(cat, 0, 64 * 3072 * sizeof(float), stream);

  pack_w12<<<8192, 256, 0, stream>>>(w1, w2, W12);
  cast4<<<3072, 256, 0, stream>>>(lin_w, linb, 3072 * 1024 / 4);
  cast_conv_w<1><<<4096, 256, 0, stream>>>(cw1, cwb);
  cast_conv_w<2><<<4096, 256, 0, stream>>>(cw2, cwb + (size_t)1 * 1024 * 1024);
  cast_conv_w<3><<<4096, 256, 0, stream>>>(cw3, cwb + (size_t)3 * 1024 * 1024);

  gather_cast<<<M_PAD, 256, 0, stream>>>(data_q, data_as, emb, X);

  proj_g<<<1032, 512, 131072, stream>>>(X, W12, b1, b2, pa);
  transpose_pq<<<256, 256, 0, stream>>>(pa, pqT);

  attn_s<<<dim3(T_ANS / 128, 4), 256, 0, stream>>>(pa, Spart);
  softmax64<<<T_ANS / 4, 256, 0, stream>>>(Spart, alpha);
  attn_y_sim<<<dim3(T_ANS / 128, 8), 256, 0, stream>>>(alpha, pqT, pa, simb);
  zero_pad_sim<<<8, 256, 0, stream>>>(simb);

  conv_g<1><<<512, 512, 131072, stream>>>(simb, cwb, cb1, cat);
  conv_g<2><<<512, 512, 131072, stream>>>(simb, cwb + (size_t)1 * 1024 * 1024, cb2, cat);
  conv_g<3><<<512, 512, 131072, stream>>>(simb, cwb + (size_t)3 * 1024 * 1024, cb3, cat);

  cast_cat<<<1536, 256, 0, stream>>>(cat, catb);
  final_h<<<dim3(1, 8), 256, 0, stream>>>(catb, linb, lin_b, h);
  final_logits<<<1, 256, 0, stream>>>(h, soft_w, soft_b, out);
}

// Round 6
// 772.686 us; speedup vs baseline: 1.2045x; 1.0175x over previous
//
#include <hip/hip_runtime.h>

#define DEV __device__ __forceinline__

typedef __bf16 bf16x8 __attribute__((ext_vector_type(8)));
typedef float f32x4 __attribute__((ext_vector_type(4)));
typedef unsigned short u16;
typedef u16 u16x4 __attribute__((ext_vector_type(4)));

constexpr int T_ANS = 32768;        // N*La answer tokens
constexpr int LQ    = 64;
constexpr int M_ALL = T_ANS + LQ;   // 32832 rows fed to projection
constexpr int M_PAD = 33024;        // 129*256 (256-tile padded)
constexpr int DIM   = 1024;

DEV u16 f2bf(float x) {
  unsigned u = __float_as_uint(x);
  return (u16)((u + 0x7FFFu + ((u >> 16) & 1u)) >> 16);
}
DEV float bf2f(u16 s) { return __uint_as_float(((unsigned)s) << 16); }

DEV void gl2lds16(const void* g, void* l) {
  __builtin_amdgcn_global_load_lds(
      (const __attribute__((address_space(1))) unsigned int*)g,
      (__attribute__((address_space(3))) unsigned int*)l, 16, 0, 0);
}

#define MF(A, B, C) __builtin_amdgcn_mfma_f32_16x16x32_bf16(A, B, C, 0, 0, 0)

// ---------------- 4-phase/K-tile 256x256 GEMM core ----------------
// LDS: [A0 32K][B0 32K][A1 32K][B1 32K]. Rows 128 B, swizzle byte ^= ((row&7)<<4).
// gl2lds dest LINEAR; global source col-block inverse-XOR'd (rule 21).
// Per K-tile group: B-frags loaded ONCE (PH0) into regs; PH1-3 load 4 A-frags each.
// Tile kt+1 staged entirely in PH0 (A) + PH1 (B) into the opposite buffer;
// single vmcnt(0) at PH3-end -> waited loads are 2-3 phases old (>= HBM latency).

DEV void stageC(const char* gk, char* ldsT, int row0, int tid) {
  const int f = tid << 4;                 // 0..8191, 64 rows per chunk
  const int r = row0 + (f >> 7);
  const int cb = ((f >> 4) & 7) ^ (r & 7);
  gl2lds16(gk + (size_t)r * 2048 + (cb << 4), ldsT + (row0 << 7) + f);
}

DEV bf16x8 LF(const char* ldsT, int row, int cbyte) {
  return *(const bf16x8*)(ldsT + (row << 7) + (cbyte ^ ((row & 7) << 4)));
}

// k-half-major MFMA order: 8 independent accs per half -> chain distance 8
#define MQUAD(Q, a00, a01, a10, a11)                                                  \
    acc[2*(Q)][0]   = MF(a00, bb00, acc[2*(Q)][0]);                                   \
    acc[2*(Q)][1]   = MF(a00, bb10, acc[2*(Q)][1]);                                   \
    acc[2*(Q)][2]   = MF(a00, bb20, acc[2*(Q)][2]);                                   \
    acc[2*(Q)][3]   = MF(a00, bb30, acc[2*(Q)][3]);                                   \
    acc[2*(Q)+1][0] = MF(a10, bb00, acc[2*(Q)+1][0]);                                 \
    acc[2*(Q)+1][1] = MF(a10, bb10, acc[2*(Q)+1][1]);                                 \
    acc[2*(Q)+1][2] = MF(a10, bb20, acc[2*(Q)+1][2]);                                 \
    acc[2*(Q)+1][3] = MF(a10, bb30, acc[2*(Q)+1][3]);                                 \
    acc[2*(Q)][0]   = MF(a01, bb01, acc[2*(Q)][0]);                                   \
    acc[2*(Q)][1]   = MF(a01, bb11, acc[2*(Q)][1]);                                   \
    acc[2*(Q)][2]   = MF(a01, bb21, acc[2*(Q)][2]);                                   \
    acc[2*(Q)][3]   = MF(a01, bb31, acc[2*(Q)][3]);                                   \
    acc[2*(Q)+1][0] = MF(a11, bb01, acc[2*(Q)+1][0]);                                 \
    acc[2*(Q)+1][1] = MF(a11, bb11, acc[2*(Q)+1][1]);                                 \
    acc[2*(Q)+1][2] = MF(a11, bb21, acc[2*(Q)+1][2]);                                 \
    acc[2*(Q)+1][3] = MF(a11, bb31, acc[2*(Q)+1][3]);

// Phase 0: load all B (8 reads) + A quadrant 0 (4); lgkm(8) pacing hint.
#define PHB(LA, LB, STAGES, VMW)                                                      \
  {                                                                                   \
    bb00 = LF(LB, wn +  0 + lr, hi16); bb01 = LF(LB, wn +  0 + lr, 64 + hi16);        \
    bb10 = LF(LB, wn + 16 + lr, hi16); bb11 = LF(LB, wn + 16 + lr, 64 + hi16);        \
    bb20 = LF(LB, wn + 32 + lr, hi16); bb21 = LF(LB, wn + 32 + lr, 64 + hi16);        \
    bb30 = LF(LB, wn + 48 + lr, hi16); bb31 = LF(LB, wn + 48 + lr, 64 + hi16);        \
    bf16x8 a00 = LF(LA, wm + lr, hi16),      a01 = LF(LA, wm + lr, 64 + hi16);        \
    bf16x8 a10 = LF(LA, wm + 16 + lr, hi16), a11 = LF(LA, wm + 16 + lr, 64 + hi16);   \
    STAGES                                                                            \
    asm volatile("s_waitcnt lgkmcnt(8)" ::: "memory");                                \
    __builtin_amdgcn_s_barrier();                                                     \
    asm volatile("s_waitcnt lgkmcnt(0)" ::: "memory");                                \
    __builtin_amdgcn_sched_barrier(0);                                                \
    __builtin_amdgcn_s_setprio(1);                                                    \
    MQUAD(0, a00, a01, a10, a11)                                                      \
    __builtin_amdgcn_s_setprio(0);                                                    \
    VMW                                                                               \
    __builtin_amdgcn_s_barrier();                                                     \
  }

// Phases 1-3: load A quadrant Q only (4 reads); MFMA with resident B.
#define PHA(Q, LA, STAGES, VMW)                                                       \
  {                                                                                   \
    bf16x8 a00 = LF(LA, wm + (2*(Q))*16 + lr, hi16);                                  \
    bf16x8 a01 = LF(LA, wm + (2*(Q))*16 + lr, 64 + hi16);                             \
    bf16x8 a10 = LF(LA, wm + (2*(Q)+1)*16 + lr, hi16);                                \
    bf16x8 a11 = LF(LA, wm + (2*(Q)+1)*16 + lr, 64 + hi16);                           \
    STAGES                                                                            \
    __builtin_amdgcn_s_barrier();                                                     \
    asm volatile("s_waitcnt lgkmcnt(0)" ::: "memory");                                \
    __builtin_amdgcn_sched_barrier(0);                                                \
    __builtin_amdgcn_s_setprio(1);                                                    \
    MQUAD(Q, a00, a01, a10, a11)                                                      \
    __builtin_amdgcn_s_setprio(0);                                                    \
    VMW                                                                               \
    __builtin_amdgcn_s_barrier();                                                     \
  }

#define VM0 asm volatile("s_waitcnt vmcnt(0)" ::: "memory"); __builtin_amdgcn_sched_barrier(0);

// KT K-tiles of 64; buffers ping-pong per tile.
#define GEMM_PIPE(KT)                                                                 \
  f32x4 acc[8][4] = {};                                                               \
  bf16x8 bb00, bb01, bb10, bb11, bb20, bb21, bb30, bb31;                              \
  stageC(Ab(0), lds, 0, tid);           stageC(Ab(0), lds, 64, tid);                  \
  stageC(Ab(0), lds, 128, tid);         stageC(Ab(0), lds, 192, tid);                 \
  stageC(Bb(0), lds + 32768, 0, tid);   stageC(Bb(0), lds + 32768, 64, tid);          \
  stageC(Bb(0), lds + 32768, 128, tid); stageC(Bb(0), lds + 32768, 192, tid);         \
  VM0                                                                                 \
  __builtin_amdgcn_s_barrier();                                                       \
  for (int kt = 0; kt < (KT) - 1; ++kt) {                                             \
    const char* LA = (kt & 1) ? lds + 65536 : lds;                                    \
    const char* LB = (kt & 1) ? lds + 98304 : lds + 32768;                            \
    char* WA = (kt & 1) ? lds : lds + 65536;                                          \
    char* WB = (kt & 1) ? lds + 32768 : lds + 98304;                                  \
    PHB(LA, LB,                                                                       \
        stageC(Ab(kt + 1), WA, 0, tid);   stageC(Ab(kt + 1), WA, 64, tid);            \
        stageC(Ab(kt + 1), WA, 128, tid); stageC(Ab(kt + 1), WA, 192, tid); , )       \
    PHA(1, LA,                                                                        \
        stageC(Bb(kt + 1), WB, 0, tid);   stageC(Bb(kt + 1), WB, 64, tid);            \
        stageC(Bb(kt + 1), WB, 128, tid); stageC(Bb(kt + 1), WB, 192, tid); , )       \
    PHA(2, LA, , )                                                                    \
    PHA(3, LA, , VM0)                                                                 \
  }                                                                                   \
  {                                                                                   \
    const char* LA = (((KT) - 1) & 1) ? lds + 65536 : lds;                            \
    const char* LB = (((KT) - 1) & 1) ? lds + 98304 : lds + 32768;                    \
    PHB(LA, LB, , )                                                                   \
    PHA(1, LA, , )                                                                    \
    PHA(2, LA, , )                                                                    \
    PHA(3, LA, , )                                                                    \
  }

// ---------------- simple cast / gather kernels ----------------

__global__ void cast4(const float* __restrict__ src, u16* __restrict__ dst, int n4) {
  int i = blockIdx.x * 256 + threadIdx.x;
  if (i < n4) {
    float4 v = ((const float4*)src)[i];
    u16x4 o = { f2bf(v.x), f2bf(v.y), f2bf(v.z), f2bf(v.w) };
    ((u16x4*)dst)[i] = o;
  }
}

// cw[o][i][k] (stride W in k) -> W matrices BT_k[o][i], k-major contiguous reads
template<int W>
__global__ void cast_conv_w(const float* __restrict__ src, u16* __restrict__ dst) {
  int i = blockIdx.x * 256 + threadIdx.x;  // over 1024*1024
  if (i < 1024 * 1024) {
#pragma unroll
    for (int k = 0; k < W; ++k)
      dst[(size_t)k * (1024 * 1024) + i] = f2bf(src[(size_t)i * W + k]);
  }
}

// W12 pack: 16-row interleave of w1/w2 so a 256-wide N-tile holds matched pairs
__global__ void pack_w12(const float* __restrict__ w1, const float* __restrict__ w2,
                         u16* __restrict__ W12) {
  int i = blockIdx.x * 256 + threadIdx.x;  // over 2048*1024
  if (i < 2048 * 1024) {
    int n2 = i >> 10, k = i & 1023;
    int j = n2 >> 4, m = n2 & 15;
    const float* src = (j & 1) ? w2 : w1;
    W12[i] = f2bf(src[(size_t)((j >> 1) * 16 + m) * 1024 + k]);
  }
}

__global__ void gather_cast(const int* __restrict__ dq, const int* __restrict__ das,
                            const float* __restrict__ emb, u16* __restrict__ X) {
  const int row = blockIdx.x;        // [0, M_PAD)
  const int c   = threadIdx.x;       // 256 threads * 4 floats = 1024
  size_t dsto = (size_t)row * DIM + c * 4;
  if (row >= M_ALL) {                // zero pad rows so GEMM tiles are clean
    u16x4 z = {0, 0, 0, 0};
    *(u16x4*)(X + dsto) = z;
    return;
  }
  const int tok = (row < T_ANS) ? das[row] : dq[row - T_ANS];
  float4 v = ((const float4*)(emb + (size_t)tok * DIM))[c];
  u16x4 o = { f2bf(v.x), f2bf(v.y), f2bf(v.z), f2bf(v.w) };
  *(u16x4*)(X + dsto) = o;
}

__global__ void transpose_pq(const u16* __restrict__ pa, u16* __restrict__ pqT) {
  int i = blockIdx.x * 256 + threadIdx.x;  // 1024*64
  int e = i >> 6, q = i & 63;
  pqT[i] = pa[(size_t)(T_ANS + q) * DIM + e];
}

__global__ void zero_pad_sim(u16* __restrict__ sim) {
  int i = blockIdx.x * 256 + threadIdx.x;
  if (i < 2 * DIM) sim[(size_t)T_ANS * DIM + i] = 0;
}

__global__ void cast_cat(const float* __restrict__ cat, u16* __restrict__ catb) {
  int i = blockIdx.x * 256 + threadIdx.x;  // 128*3072
  if (i < 128 * 3072) {
    int row = i / 3072;
    catb[i] = (row < 64) ? f2bf(cat[i]) : (u16)0;
  }
}

// ---------------- projection: pa = sig(X@w1^T+b1)*tanh(X@w2^T+b2) ------------------
// One GEMM M=33024, N=2048 (interleaved W12), K=1024 (KT=16). 1D grid 1032, XCD-swizzled.

__global__ __launch_bounds__(512, 1)
void proj_g(const u16* __restrict__ X, const u16* __restrict__ W12,
            const float* __restrict__ b1, const float* __restrict__ b2,
            u16* __restrict__ pa) {
  extern __shared__ char lds[];
  const int tid = threadIdx.x, lane = tid & 63;
  const int wid = tid >> 6;
  const int wm = (wid >> 2) * 128, wn = (wid & 3) * 64;
  const int lr = lane & 15, hi16 = (lane >> 4) * 16;
  // bijective XCD swizzle: 1032 = 8*129; same-A blocks (all 8 tn) contiguous per XCD
  const int wg = ((int)blockIdx.x % 8) * 129 + (int)blockIdx.x / 8;
  const int tm = (wg >> 3) * 256, tn = (wg & 7) * 256;
  const char* Ag = (const char*)X + (size_t)tm * 2048;
  const char* Bg = (const char*)W12 + (size_t)tn * 2048;
  auto Ab = [&](int kt) { return Ag + ((kt & 15) << 7); };
  auto Bb = [&](int kt) { return Bg + ((kt & 15) << 7); };

  GEMM_PIPE(16)

  // epilogue: gate, then LDS bounce (stride 132 u16), then coalesced u16x4 streams
  u16* cw = (u16*)lds;
  const int lg = (lane >> 4) * 4;
#pragma unroll
  for (int pp = 0; pp < 2; ++pp) {
    const int clocal = ((wn >> 5) + pp) * 16 + lr;   // 0..127
    const int col = (tn >> 1) + clocal;
    const float b1v = b1[col], b2v = b2[col];
#pragma unroll
    for (int mi = 0; mi < 8; ++mi)
#pragma unroll
      for (int r = 0; r < 4; ++r) {
        const int rowL = wm + mi * 16 + lg + r;
        const float x1 = acc[mi][2 * pp][r] + b1v;
        const float x2 = acc[mi][2 * pp + 1][r] + b2v;
        const float sg = 1.f / (1.f + __expf(-x1));
        const float th = 2.f / (1.f + __expf(-2.f * x2)) - 1.f;
        cw[rowL * 132 + clocal] = f2bf(sg * th);
      }
  }
  __syncthreads();
#pragma unroll
  for (int it = 0; it < 16; ++it) {
    const int cid = it * 512 + tid;                  // 8192 chunks of 4 u16
    const int rowL = cid >> 5, c4 = (cid & 31) * 4;
    u16x4 v = *(const u16x4*)(cw + rowL * 132 + c4);
    *(u16x4*)(pa + (size_t)(tm + rowL) * DIM + (tn >> 1) + c4) = v;
  }
}

// ---------------- conv (window W) + relu + per-answer DMax -------------------------
// GEMM M=32768, N=1024, K=W*1024; tap = kt/16 shifts A rows & selects B slab.

template<int W>
__global__ __launch_bounds__(512, 1)
void conv_g(const u16* __restrict__ sim, const u16* __restrict__ Bw,
            const float* __restrict__ cb, float* __restrict__ cat) {
  extern __shared__ char lds[];
  const int tid = threadIdx.x, lane = tid & 63;
  const int wid = tid >> 6;
  const int wm = (wid >> 2) * 128, wn = (wid & 3) * 64;
  const int lr = lane & 15, hi16 = (lane >> 4) * 16;
  // bijective XCD swizzle: 512 = 8*64; same-A blocks (all 4 tn) contiguous per XCD
  const int wg = ((int)blockIdx.x % 8) * 64 + (int)blockIdx.x / 8;
  const int tm = (wg >> 2) * 256, tn = (wg & 3) * 256;
  const char* Ag = (const char*)sim + (size_t)tm * 2048;
  const char* Bg = (const char*)Bw + (size_t)tn * 2048;
  auto Ab = [&](int kt) { return Ag + (kt >> 4) * 2048 + ((kt & 15) << 7); };
  auto Bb = [&](int kt) { return Bg + (size_t)(kt >> 4) * 2097152 + ((kt & 15) << 7); };

  GEMM_PIPE(16 * W)

  // epilogue: +cb, relu, mask boundary rows, column max, atomicMax into cat
  const int lg = (lane >> 4) * 4;
  const int n = tm >> 9;  // 256 | 512 so one answer per tile
#pragma unroll
  for (int ni = 0; ni < 4; ++ni) {
    const int col = tn + wn + ni * 16 + lr;
    const float cbv = cb[col];
    float vmax = 0.f;
#pragma unroll
    for (int mi = 0; mi < 8; ++mi)
#pragma unroll
      for (int r = 0; r < 4; ++r) {
        const int t = tm + wm + mi * 16 + lg + r;
        float v = fmaxf(acc[mi][ni][r] + cbv, 0.f);
        if ((t & 511) > 512 - W) v = 0.f;  // window straddles answer boundary
        vmax = fmaxf(vmax, v);
      }
    vmax = fmaxf(vmax, __shfl_xor(vmax, 16));
    vmax = fmaxf(vmax, __shfl_xor(vmax, 32));
    if (lane < 16)
      atomicMax((int*)&cat[(size_t)n * 3072 + (W - 1) * 1024 + col], __float_as_int(vmax));
  }
}

// ---------------- attention S = pa @ pq^T  (split-K x4, deterministic partials) ----

__global__ __launch_bounds__(256, 2)
void attn_s(const u16* __restrict__ pa, float* __restrict__ Spart) {
  __shared__ alignas(16) u16 sA[128 * 32];
  __shared__ alignas(16) u16 sB[64 * 32];
  const int tid = threadIdx.x, lane = tid & 63;
  const int tm = blockIdx.x * 128;
  const int kbase = blockIdx.y * 256;     // K chunk of 256
  const int wid = tid >> 6;
  const int wm = (wid >> 1) * 64, wn = (wid & 1) * 32;
  const u16* pq = pa + (size_t)T_ANS * DIM;
  f32x4 acc[4][2] = {};
  for (int k0 = kbase; k0 < kbase + 256; k0 += 32) {
#pragma unroll
    for (int j = 0; j < 2; ++j) {
      const int f = tid * 16 + j * 4096;
      const int r = f >> 6, cb = f & 63;
      gl2lds16((const char*)pa + (size_t)(tm + r) * 2048 + k0 * 2 + cb, (char*)sA + f);
    }
    {
      const int f = tid * 16;  // 4 KB, single issue
      const int r = f >> 6, cb = f & 63;
      gl2lds16((const char*)pq + (size_t)r * 2048 + k0 * 2 + cb, (char*)sB + f);
    }
    __syncthreads();
    const int lr = lane & 15, lk = (lane >> 4) * 8;
    bf16x8 af[4], bfr[2];
#pragma unroll
    for (int i = 0; i < 4; ++i)
      af[i] = *(const bf16x8*)(sA + (wm + i * 16 + lr) * 32 + lk);
#pragma unroll
    for (int i = 0; i < 2; ++i)
      bfr[i] = *(const bf16x8*)(sB + (wn + i * 16 + lr) * 32 + lk);
#pragma unroll
    for (int mi = 0; mi < 4; ++mi)
#pragma unroll
      for (int ni = 0; ni < 2; ++ni)
        acc[mi][ni] = MF(af[mi], bfr[ni], acc[mi][ni]);
    __syncthreads();
  }
  const int lr = lane & 15, lg = (lane >> 4) * 4;
  float* Sp = Spart + (size_t)blockIdx.y * (T_ANS * 64);
#pragma unroll
  for (int mi = 0; mi < 4; ++mi)
#pragma unroll
    for (int ni = 0; ni < 2; ++ni)
#pragma unroll
      for (int r = 0; r < 4; ++r) {
        const int row = tm + wm + mi * 16 + lg + r;
        const int col = wn + ni * 16 + lr;
        Sp[(size_t)row * 64 + col] = acc[mi][ni][r];
      }
}

__global__ void softmax64(const float* __restrict__ Spart, u16* __restrict__ alpha) {
  const int row = blockIdx.x * 4 + (threadIdx.x >> 6);
  const int lane = threadIdx.x & 63;
  const size_t o = (size_t)row * 64 + lane;
  float v = Spart[o] + Spart[(size_t)1 * T_ANS * 64 + o]
          + Spart[(size_t)2 * T_ANS * 64 + o] + Spart[(size_t)3 * T_ANS * 64 + o];
  float m = v;
#pragma unroll
  for (int o2 = 32; o2 > 0; o2 >>= 1) m = fmaxf(m, __shfl_xor(m, o2));
  const float e = __expf(v - m);
  float s = e;
#pragma unroll
  for (int o2 = 32; o2 > 0; o2 >>= 1) s += __shfl_xor(s, o2);
  alpha[(size_t)row * 64 + lane] = f2bf(e / s);
}

// ---------------- Y = alpha @ pq ; sim = pa * Y ----------------

__global__ __launch_bounds__(256, 2)
void attn_y_sim(const u16* __restrict__ alpha, const u16* __restrict__ pqT,
                const u16* __restrict__ pa, u16* __restrict__ sim) {
  __shared__ alignas(16) u16 sA[128 * 32];
  __shared__ alignas(16) u16 sB[128 * 32];
  const int tid = threadIdx.x, lane = tid & 63;
  const int tm = blockIdx.x * 128, tn = blockIdx.y * 128;
  const int wid = tid >> 6;
  const int wm = (wid >> 1) * 64, wn = (wid & 1) * 64;
  f32x4 acc[4][4] = {};
  for (int k0 = 0; k0 < 64; k0 += 32) {
#pragma unroll
    for (int j = 0; j < 2; ++j) {
      const int f = tid * 16 + j * 4096;
      const int r = f >> 6, cb = f & 63;
      gl2lds16((const char*)alpha + (size_t)(tm + r) * 128 + k0 * 2 + cb, (char*)sA + f);
      gl2lds16((const char*)pqT   + (size_t)(tn + r) * 128 + k0 * 2 + cb, (char*)sB + f);
    }
    __syncthreads();
    const int lr = lane & 15, lk = (lane >> 4) * 8;
    bf16x8 af[4], bfr[4];
#pragma unroll
    for (int i = 0; i < 4; ++i) {
      af[i]  = *(const bf16x8*)(sA + (wm + i * 16 + lr) * 32 + lk);
      bfr[i] = *(const bf16x8*)(sB + (wn + i * 16 + lr) * 32 + lk);
    }
#pragma unroll
    for (int mi = 0; mi < 4; ++mi)
#pragma unroll
      for (int ni = 0; ni < 4; ++ni)
        acc[mi][ni] = MF(af[mi], bfr[ni], acc[mi][ni]);
    __syncthreads();
  }
  const int lr = lane & 15, lg = (lane >> 4) * 4;
#pragma unroll
  for (int ni = 0; ni < 4; ++ni) {
    const int col = tn + wn + ni * 16 + lr;
#pragma unroll
    for (int mi = 0; mi < 4; ++mi)
#pragma unroll
      for (int r = 0; r < 4; ++r) {
        const int row = tm + wm + mi * 16 + lg + r;
        const size_t o = (size_t)row * DIM + col;
        sim[o] = f2bf(bf2f(pa[o]) * acc[mi][ni][r]);
      }
  }
}

// ---------------- final: h = tanh(cat @ lin^T + b) ----------------

__global__ __launch_bounds__(256, 2)
void final_h(const u16* __restrict__ catb, const u16* __restrict__ linb,
             const float* __restrict__ lin_b, float* __restrict__ h) {
  __shared__ alignas(16) u16 sA[128 * 32];
  __shared__ alignas(16) u16 sB[128 * 32];
  const int tid = threadIdx.x, lane = tid & 63;
  const int tn = blockIdx.y * 128;
  const int wid = tid >> 6;
  const int wm = (wid >> 1) * 64, wn = (wid & 1) * 64;
  f32x4 acc[4][4] = {};
  for (int k0 = 0; k0 < 3072; k0 += 32) {
#pragma unroll
    for (int j = 0; j < 2; ++j) {
      const int f = tid * 16 + j * 4096;
      const int r = f >> 6, cb = f & 63;
      gl2lds16((const char*)catb + (size_t)r * 6144 + k0 * 2 + cb, (char*)sA + f);
      gl2lds16((const char*)linb + (size_t)(tn + r) * 6144 + k0 * 2 + cb, (char*)sB + f);
    }
    __syncthreads();
    const int lr = lane & 15, lk = (lane >> 4) * 8;
    bf16x8 af[4], bfr[4];
#pragma unroll
    for (int i = 0; i < 4; ++i) {
      af[i]  = *(const bf16x8*)(sA + (wm + i * 16 + lr) * 32 + lk);
      bfr[i] = *(const bf16x8*)(sB + (wn + i * 16 + lr) * 32 + lk);
    }
#pragma unroll
    for (int mi = 0; mi < 4; ++mi)
#pragma unroll
      for (int ni = 0; ni < 4; ++ni)
        acc[mi][ni] = MF(af[mi], bfr[ni], acc[mi][ni]);
    __syncthreads();
  }
  const int lr = lane & 15, lg = (lane >> 4) * 4;
#pragma unroll
  for (int ni = 0; ni < 4; ++ni) {
    const int col = tn + wn + ni * 16 + lr;
    const float bv = lin_b[col];
#pragma unroll
    for (int mi = 0; mi < 4; ++mi)
#pragma unroll
      for (int r = 0; r < 4; ++r) {
        const int row = wm + mi * 16 + lg + r;
        if (row < 64) {
          const float x = acc[mi][ni][r] + bv;
          h[(size_t)row * DIM + col] = 2.f / (1.f + __expf(-2.f * x)) - 1.f;
        }
      }
  }
}

__global__ void final_logits(const float* __restrict__ h, const float* __restrict__ soft_w,
                             const float* __restrict__ soft_b, float* __restrict__ out) {
  __shared__ float part[256];
  const int t = threadIdx.x;
  const int n = t >> 2, q = t & 3;
  float s = 0.f;
  for (int j = q * 256; j < q * 256 + 256; ++j) s += h[(size_t)n * DIM + j] * soft_w[j];
  part[t] = s;
  __syncthreads();
  if (t < 64) {
    float logit = part[t * 4] + part[t * 4 + 1] + part[t * 4 + 2] + part[t * 4 + 3] + soft_b[0];
    float m = logit;
#pragma unroll
    for (int o = 32; o > 0; o >>= 1) m = fmaxf(m, __shfl_xor(m, o));
    float e = __expf(logit - m);
    float ssum = e;
#pragma unroll
    for (int o = 32; o > 0; o >>= 1) ssum += __shfl_xor(ssum, o);
    out[t] = (logit - m) - logf(ssum);
  }
}

// ---------------- launcher ----------------

extern "C" void kernel_launch(void* const* d_in, const int* in_sizes, int n_in,
                              void* d_out, int out_size, void* d_ws, size_t ws_size,
                              hipStream_t stream) {
  const int*   data_q  = (const int*)d_in[0];
  const int*   data_as = (const int*)d_in[1];
  const float* emb     = (const float*)d_in[2];
  const float* w1      = (const float*)d_in[3];
  const float* b1      = (const float*)d_in[4];
  const float* w2      = (const float*)d_in[5];
  const float* b2      = (const float*)d_in[6];
  const float* cw1     = (const float*)d_in[7];
  const float* cb1     = (const float*)d_in[8];
  const float* cw2     = (const float*)d_in[9];
  const float* cb2     = (const float*)d_in[10];
  const float* cw3     = (const float*)d_in[11];
  const float* cb3     = (const float*)d_in[12];
  const float* lin_w   = (const float*)d_in[13];
  const float* lin_b   = (const float*)d_in[14];
  const float* soft_w  = (const float*)d_in[15];
  const float* soft_b  = (const float*)d_in[16];
  float* out = (float*)d_out;

  // allow 128 KiB dynamic LDS on the pipelined kernels (host attr set, capture-safe)
  hipFuncSetAttribute((const void*)proj_g, hipFuncAttributeMaxDynamicSharedMemorySize, 131072);
  hipFuncSetAttribute((const void*)conv_g<1>, hipFuncAttributeMaxDynamicSharedMemorySize, 131072);
  hipFuncSetAttribute((const void*)conv_g<2>, hipFuncAttributeMaxDynamicSharedMemorySize, 131072);
  hipFuncSetAttribute((const void*)conv_g<3>, hipFuncAttributeMaxDynamicSharedMemorySize, 131072);

  // workspace layout (~167 MB total)
  u16* X     = (u16*)d_ws;                         // [M_PAD][1024] bf16; reused: Spart, then sim
  u16* pa    = X    + (size_t)M_PAD * DIM;         // [M_PAD][1024] bf16 (rows T..T+63 = pq)
  u16* W12   = pa   + (size_t)M_PAD * DIM;         // [2048][1024] interleaved w1/w2
  u16* cwb   = W12  + (size_t)2 * 1024 * 1024;     // 6 x [1024][1024]
  u16* linb  = cwb  + (size_t)6 * 1024 * 1024;     // [1024][3072]
  u16* pqT   = linb + (size_t)3 * 1024 * 1024;     // [1024][64]
  u16* alpha = pqT  + 64 * 1024;                   // [T][64] bf16
  float* cat = (float*)(alpha + (size_t)T_ANS * 64);  // [64][3072] f32 pools
  u16* catb  = (u16*)(cat + 64 * 3072);            // [128][3072] bf16 (rows 64+ zero)
  float* h   = (float*)(catb + 128 * 3072);        // [64][1024] f32
  u16* simb  = X;                                  // alias: [T+2][1024] bf16
  float* Spart = (float*)X;                        // alias: [4][T][64] f32 (33.6 MB < 67 MB)

  hipMemsetAsync(cat, 0, 64 * 3072 * sizeof(float), stream);

  pack_w12<<<8192, 256, 0, stream>>>(w1, w2, W12);
  cast4<<<3072, 256, 0, stream>>>(lin_w, linb, 3072 * 1024 / 4);
  cast_conv_w<1><<<4096, 256, 0, stream>>>(cw1, cwb);
  cast_conv_w<2><<<4096, 256, 0, stream>>>(cw2, cwb + (size_t)1 * 1024 * 1024);
  cast_conv_w<3><<<4096, 256, 0, stream>>>(cw3, cwb + (size_t)3 * 1024 * 1024);

  gather_cast<<<M_PAD, 256, 0, stream>>>(data_q, data_as, emb, X);

  proj_g<<<1032, 512, 131072, stream>>>(X, W12, b1, b2, pa);
  transpose_pq<<<256, 256, 0, stream>>>(pa, pqT);

  attn_s<<<dim3(T_ANS / 128, 4), 256, 0, stream>>>(pa, Spart);
  softmax64<<<T_ANS / 4, 256, 0, stream>>>(Spart, alpha);
  attn_y_sim<<<dim3(T_ANS / 128, 8), 256, 0, stream>>>(alpha, pqT, pa, simb);
  zero_pad_sim<<<8, 256, 0, stream>>>(simb);

  conv_g<1><<<512, 512, 131072, stream>>>(simb, cwb, cb1, cat);
  conv_g<2><<<512, 512, 131072, stream>>>(simb, cwb + (size_t)1 * 1024 * 1024, cb2, cat);
  conv_g<3><<<512, 512, 131072, stream>>>(simb, cwb + (size_t)3 * 1024 * 1024, cb3, cat);

  cast_cat<<<1536, 256, 0, stream>>>(cat, catb);
  final_h<<<dim3(1, 8), 256, 0, stream>>>(catb, linb, lin_b, h);
  final_logits<<<1, 256, 0, stream>>>(h, soft_w, soft_b, out);
}

// Round 7
// 763.140 us; speedup vs baseline: 1.2196x; 1.0125x over previous
//
#include <hip/hip_runtime.h>

#define DEV __device__ __forceinline__

typedef __bf16 bf16x8 __attribute__((ext_vector_type(8)));
typedef float f32x4 __attribute__((ext_vector_type(4)));
typedef unsigned short u16;
typedef u16 u16x4 __attribute__((ext_vector_type(4)));

constexpr int T_ANS = 32768;        // N*La answer tokens
constexpr int LQ    = 64;
constexpr int M_ALL = T_ANS + LQ;   // 32832 rows fed to projection
constexpr int M_PAD = 33024;        // 129*256 (256-tile padded)
constexpr int DIM   = 1024;

DEV u16 f2bf(float x) {
  unsigned u = __float_as_uint(x);
  return (u16)((u + 0x7FFFu + ((u >> 16) & 1u)) >> 16);
}
DEV float bf2f(u16 s) { return __uint_as_float(((unsigned)s) << 16); }

DEV void gl2lds16(const void* g, void* l) {
  __builtin_amdgcn_global_load_lds(
      (const __attribute__((address_space(1))) unsigned int*)g,
      (__attribute__((address_space(3))) unsigned int*)l, 16, 0, 0);
}

#define MF(A, B, C) __builtin_amdgcn_mfma_f32_16x16x32_bf16(A, B, C, 0, 0, 0)

// ---------------- 4-phase/K-tile 256x256 GEMM core (hoisted addressing) ----------
// LDS: [A0 32K][B0 32K][A1 32K][B1 32K]. Rows 128 B, swizzle block ^= (row&7).
// Since wm,wn = 0 mod 8 and frag-row offsets = 0 mod 16, row&7 == lane&7 for every
// fragment -> swizzle is lane-constant -> 8 precomputed base pointers; every read is
// ds_read_b128 base+imm (zero per-phase VALU). Stage offsets (gOff/tidOff) hoisted too.
// Schedule identical to R6: per K-tile {PH0: 8B+4A reads, stage A(kt+1); PH1: 4A,
// stage B(kt+1); PH2: 4A; PH3: 4A + vmcnt(0)}; barriers around each MFMA cluster.

#define LFC(BASE, OFF) (*(const bf16x8*)((BASE) + (OFF)))

#define STG(G, LT, R0) gl2lds16((G) + (R0) * 2048 + gOff, (LT) + (R0) * 128 + tidOff)

// k-half-major MFMA order: 8 independent accs per half -> chain distance 8
#define MQUAD(Q, a00, a01, a10, a11)                                                  \
    acc[2*(Q)][0]   = MF(a00, bb00, acc[2*(Q)][0]);                                   \
    acc[2*(Q)][1]   = MF(a00, bb10, acc[2*(Q)][1]);                                   \
    acc[2*(Q)][2]   = MF(a00, bb20, acc[2*(Q)][2]);                                   \
    acc[2*(Q)][3]   = MF(a00, bb30, acc[2*(Q)][3]);                                   \
    acc[2*(Q)+1][0] = MF(a10, bb00, acc[2*(Q)+1][0]);                                 \
    acc[2*(Q)+1][1] = MF(a10, bb10, acc[2*(Q)+1][1]);                                 \
    acc[2*(Q)+1][2] = MF(a10, bb20, acc[2*(Q)+1][2]);                                 \
    acc[2*(Q)+1][3] = MF(a10, bb30, acc[2*(Q)+1][3]);                                 \
    acc[2*(Q)][0]   = MF(a01, bb01, acc[2*(Q)][0]);                                   \
    acc[2*(Q)][1]   = MF(a01, bb11, acc[2*(Q)][1]);                                   \
    acc[2*(Q)][2]   = MF(a01, bb21, acc[2*(Q)][2]);                                   \
    acc[2*(Q)][3]   = MF(a01, bb31, acc[2*(Q)][3]);                                   \
    acc[2*(Q)+1][0] = MF(a11, bb01, acc[2*(Q)+1][0]);                                 \
    acc[2*(Q)+1][1] = MF(a11, bb11, acc[2*(Q)+1][1]);                                 \
    acc[2*(Q)+1][2] = MF(a11, bb21, acc[2*(Q)+1][2]);                                 \
    acc[2*(Q)+1][3] = MF(a11, bb31, acc[2*(Q)+1][3]);

#define BARW                                                                          \
    __builtin_amdgcn_s_barrier();                                                     \
    asm volatile("s_waitcnt lgkmcnt(0)" ::: "memory");                                \
    __builtin_amdgcn_sched_barrier(0);

#define VM0 asm volatile("s_waitcnt vmcnt(0)" ::: "memory"); __builtin_amdgcn_sched_barrier(0);

// One K-tile = 4 phases on buffers (Ac0,Ac1,Bc0,Bc1); S0/S1 = stage blocks; VMWv at PH3.
#define TILE(Ac0, Ac1, Bc0, Bc1, S0, S1, VMWv)                                        \
  { /* PH0: all B + A quadrant 0 */                                                   \
    bb00 = LFC(Bc0, 0);    bb01 = LFC(Bc1, 0);                                        \
    bb10 = LFC(Bc0, 2048); bb11 = LFC(Bc1, 2048);                                     \
    bb20 = LFC(Bc0, 4096); bb21 = LFC(Bc1, 4096);                                     \
    bb30 = LFC(Bc0, 6144); bb31 = LFC(Bc1, 6144);                                     \
    bf16x8 a00 = LFC(Ac0, 0),    a01 = LFC(Ac1, 0);                                   \
    bf16x8 a10 = LFC(Ac0, 2048), a11 = LFC(Ac1, 2048);                                \
    S0                                                                                \
    asm volatile("s_waitcnt lgkmcnt(8)" ::: "memory");                                \
    BARW                                                                              \
    __builtin_amdgcn_s_setprio(1); MQUAD(0, a00, a01, a10, a11)                       \
    __builtin_amdgcn_s_setprio(0);                                                    \
    __builtin_amdgcn_s_barrier();                                                     \
  }                                                                                   \
  { /* PH1 */                                                                         \
    bf16x8 a00 = LFC(Ac0, 4096), a01 = LFC(Ac1, 4096);                                \
    bf16x8 a10 = LFC(Ac0, 6144), a11 = LFC(Ac1, 6144);                                \
    S1                                                                                \
    BARW                                                                              \
    __builtin_amdgcn_s_setprio(1); MQUAD(1, a00, a01, a10, a11)                       \
    __builtin_amdgcn_s_setprio(0);                                                    \
    __builtin_amdgcn_s_barrier();                                                     \
  }                                                                                   \
  { /* PH2 */                                                                         \
    bf16x8 a00 = LFC(Ac0, 8192),  a01 = LFC(Ac1, 8192);                               \
    bf16x8 a10 = LFC(Ac0, 10240), a11 = LFC(Ac1, 10240);                              \
    BARW                                                                              \
    __builtin_amdgcn_s_setprio(1); MQUAD(2, a00, a01, a10, a11)                       \
    __builtin_amdgcn_s_setprio(0);                                                    \
    __builtin_amdgcn_s_barrier();                                                     \
  }                                                                                   \
  { /* PH3 */                                                                         \
    bf16x8 a00 = LFC(Ac0, 12288), a01 = LFC(Ac1, 12288);                              \
    bf16x8 a10 = LFC(Ac0, 14336), a11 = LFC(Ac1, 14336);                              \
    BARW                                                                              \
    __builtin_amdgcn_s_setprio(1); MQUAD(3, a00, a01, a10, a11)                       \
    __builtin_amdgcn_s_setprio(0);                                                    \
    VMWv                                                                              \
    __builtin_amdgcn_s_barrier();                                                     \
  }

#define S_A(G, LT) { const char* g_ = (G); STG(g_, LT, 0); STG(g_, LT, 64); STG(g_, LT, 128); STG(g_, LT, 192); }

// KT K-tiles of 64; buffers ping-pong per tile (compile-time via 2-tile unroll).
#define GEMM_PIPE(KT)                                                                 \
  f32x4 acc[8][4] = {};                                                               \
  bf16x8 bb00, bb01, bb10, bb11, bb20, bb21, bb30, bb31;                              \
  const int e_ = lane & 7, h_ = lane >> 4, blk0 = (h_ ^ e_) << 4, blk1 = ((h_ ^ e_) ^ 4) << 4; \
  const int rA0 = (wm + lr) * 128, rB0 = (wn + lr) * 128;                             \
  const char* A0c0 = lds + rA0 + blk0;          const char* A0c1 = lds + rA0 + blk1;  \
  const char* B0c0 = lds + 32768 + rB0 + blk0;  const char* B0c1 = lds + 32768 + rB0 + blk1; \
  const char* A1c0 = lds + 65536 + rA0 + blk0;  const char* A1c1 = lds + 65536 + rA0 + blk1; \
  const char* B1c0 = lds + 98304 + rB0 + blk0;  const char* B1c1 = lds + 98304 + rB0 + blk1; \
  char* ldsA0 = lds;          char* ldsB0 = lds + 32768;                              \
  char* ldsA1 = lds + 65536;  char* ldsB1 = lds + 98304;                              \
  const int tidOff = tid * 16;                                                        \
  const int gOff = (tid >> 3) * 2048 + (((tid & 7) ^ ((tid >> 3) & 7)) << 4);         \
  S_A(Ab(0), ldsA0) S_A(Bb(0), ldsB0)                                                 \
  VM0                                                                                 \
  __builtin_amdgcn_s_barrier();                                                       \
  for (int kp = 0; kp < (KT) / 2 - 1; ++kp) {                                         \
    const int k1 = 2 * kp + 1;                                                        \
    TILE(A0c0, A0c1, B0c0, B0c1, S_A(Ab(k1), ldsA1), S_A(Bb(k1), ldsB1), VM0)         \
    TILE(A1c0, A1c1, B1c0, B1c1, S_A(Ab(k1 + 1), ldsA0), S_A(Bb(k1 + 1), ldsB0), VM0) \
  }                                                                                   \
  TILE(A0c0, A0c1, B0c0, B0c1, S_A(Ab((KT) - 1), ldsA1), S_A(Bb((KT) - 1), ldsB1), VM0) \
  TILE(A1c0, A1c1, B1c0, B1c1, , , )

// ---------------- simple cast / gather kernels ----------------

__global__ void cast4(const float* __restrict__ src, u16* __restrict__ dst, int n4) {
  int i = blockIdx.x * 256 + threadIdx.x;
  if (i < n4) {
    float4 v = ((const float4*)src)[i];
    u16x4 o = { f2bf(v.x), f2bf(v.y), f2bf(v.z), f2bf(v.w) };
    ((u16x4*)dst)[i] = o;
  }
}

// cw[o][i][k] (stride W in k) -> W matrices BT_k[o][i], k-major contiguous reads
template<int W>
__global__ void cast_conv_w(const float* __restrict__ src, u16* __restrict__ dst) {
  int i = blockIdx.x * 256 + threadIdx.x;  // over 1024*1024
  if (i < 1024 * 1024) {
#pragma unroll
    for (int k = 0; k < W; ++k)
      dst[(size_t)k * (1024 * 1024) + i] = f2bf(src[(size_t)i * W + k]);
  }
}

// W12 pack: 16-row interleave of w1/w2 so a 256-wide N-tile holds matched pairs
__global__ void pack_w12(const float* __restrict__ w1, const float* __restrict__ w2,
                         u16* __restrict__ W12) {
  int i = blockIdx.x * 256 + threadIdx.x;  // over 2048*1024
  if (i < 2048 * 1024) {
    int n2 = i >> 10, k = i & 1023;
    int j = n2 >> 4, m = n2 & 15;
    const float* src = (j & 1) ? w2 : w1;
    W12[i] = f2bf(src[(size_t)((j >> 1) * 16 + m) * 1024 + k]);
  }
}

__global__ void gather_cast(const int* __restrict__ dq, const int* __restrict__ das,
                            const float* __restrict__ emb, u16* __restrict__ X) {
  const int row = blockIdx.x;        // [0, M_PAD)
  const int c   = threadIdx.x;       // 256 threads * 4 floats = 1024
  size_t dsto = (size_t)row * DIM + c * 4;
  if (row >= M_ALL) {                // zero pad rows so GEMM tiles are clean
    u16x4 z = {0, 0, 0, 0};
    *(u16x4*)(X + dsto) = z;
    return;
  }
  const int tok = (row < T_ANS) ? das[row] : dq[row - T_ANS];
  float4 v = ((const float4*)(emb + (size_t)tok * DIM))[c];
  u16x4 o = { f2bf(v.x), f2bf(v.y), f2bf(v.z), f2bf(v.w) };
  *(u16x4*)(X + dsto) = o;
}

__global__ void transpose_pq(const u16* __restrict__ pa, u16* __restrict__ pqT) {
  int i = blockIdx.x * 256 + threadIdx.x;  // 1024*64
  int e = i >> 6, q = i & 63;
  pqT[i] = pa[(size_t)(T_ANS + q) * DIM + e];
}

__global__ void zero_pad_sim(u16* __restrict__ sim) {
  int i = blockIdx.x * 256 + threadIdx.x;
  if (i < 2 * DIM) sim[(size_t)T_ANS * DIM + i] = 0;
}

__global__ void cast_cat(const float* __restrict__ cat, u16* __restrict__ catb) {
  int i = blockIdx.x * 256 + threadIdx.x;  // 128*3072
  if (i < 128 * 3072) {
    int row = i / 3072;
    catb[i] = (row < 64) ? f2bf(cat[i]) : (u16)0;
  }
}

// ---------------- projection: pa = sig(X@w1^T+b1)*tanh(X@w2^T+b2) ------------------
// One GEMM M=33024, N=2048 (interleaved W12), K=1024 (KT=16). 1D grid 1032, XCD-swizzled.

__global__ __launch_bounds__(512, 1)
void proj_g(const u16* __restrict__ X, const u16* __restrict__ W12,
            const float* __restrict__ b1, const float* __restrict__ b2,
            u16* __restrict__ pa) {
  extern __shared__ char lds[];
  const int tid = threadIdx.x, lane = tid & 63;
  const int wid = tid >> 6;
  const int wm = (wid >> 2) * 128, wn = (wid & 3) * 64;
  const int lr = lane & 15;
  // bijective XCD swizzle: 1032 = 8*129; same-A blocks (all 8 tn) contiguous per XCD
  const int wg = ((int)blockIdx.x % 8) * 129 + (int)blockIdx.x / 8;
  const int tm = (wg >> 3) * 256, tn = (wg & 7) * 256;
  const char* Ag = (const char*)X + (size_t)tm * 2048;
  const char* Bg = (const char*)W12 + (size_t)tn * 2048;
  auto Ab = [&](int kt) { return Ag + ((kt & 15) << 7); };
  auto Bb = [&](int kt) { return Bg + ((kt & 15) << 7); };

  GEMM_PIPE(16)

  // epilogue: gate, then LDS bounce (stride 132 u16), then coalesced u16x4 streams
  u16* cw = (u16*)lds;
  const int lg = (lane >> 4) * 4;
#pragma unroll
  for (int pp = 0; pp < 2; ++pp) {
    const int clocal = ((wn >> 5) + pp) * 16 + lr;   // 0..127
    const int col = (tn >> 1) + clocal;
    const float b1v = b1[col], b2v = b2[col];
#pragma unroll
    for (int mi = 0; mi < 8; ++mi)
#pragma unroll
      for (int r = 0; r < 4; ++r) {
        const int rowL = wm + mi * 16 + lg + r;
        const float x1 = acc[mi][2 * pp][r] + b1v;
        const float x2 = acc[mi][2 * pp + 1][r] + b2v;
        const float sg = 1.f / (1.f + __expf(-x1));
        const float th = 2.f / (1.f + __expf(-2.f * x2)) - 1.f;
        cw[rowL * 132 + clocal] = f2bf(sg * th);
      }
  }
  __syncthreads();
#pragma unroll
  for (int it = 0; it < 16; ++it) {
    const int cid = it * 512 + tid;                  // 8192 chunks of 4 u16
    const int rowL = cid >> 5, c4 = (cid & 31) * 4;
    u16x4 v = *(const u16x4*)(cw + rowL * 132 + c4);
    *(u16x4*)(pa + (size_t)(tm + rowL) * DIM + (tn >> 1) + c4) = v;
  }
}

// ---------------- conv (window W) + relu + per-answer DMax -------------------------
// GEMM M=32768, N=1024, K=W*1024; tap = kt/16 shifts A rows & selects B slab.

template<int W>
__global__ __launch_bounds__(512, 1)
void conv_g(const u16* __restrict__ sim, const u16* __restrict__ Bw,
            const float* __restrict__ cb, float* __restrict__ cat) {
  extern __shared__ char lds[];
  const int tid = threadIdx.x, lane = tid & 63;
  const int wid = tid >> 6;
  const int wm = (wid >> 2) * 128, wn = (wid & 3) * 64;
  const int lr = lane & 15;
  // bijective XCD swizzle: 512 = 8*64; same-A blocks (all 4 tn) contiguous per XCD
  const int wg = ((int)blockIdx.x % 8) * 64 + (int)blockIdx.x / 8;
  const int tm = (wg >> 2) * 256, tn = (wg & 3) * 256;
  const char* Ag = (const char*)sim + (size_t)tm * 2048;
  const char* Bg = (const char*)Bw + (size_t)tn * 2048;
  auto Ab = [&](int kt) { return Ag + (kt >> 4) * 2048 + ((kt & 15) << 7); };
  auto Bb = [&](int kt) { return Bg + (size_t)(kt >> 4) * 2097152 + ((kt & 15) << 7); };

  GEMM_PIPE(16 * W)

  // epilogue: +cb, relu, mask boundary rows, column max, atomicMax into cat
  const int lg = (lane >> 4) * 4;
  const int n = tm >> 9;  // 256 | 512 so one answer per tile
#pragma unroll
  for (int ni = 0; ni < 4; ++ni) {
    const int col = tn + wn + ni * 16 + lr;
    const float cbv = cb[col];
    float vmax = 0.f;
#pragma unroll
    for (int mi = 0; mi < 8; ++mi)
#pragma unroll
      for (int r = 0; r < 4; ++r) {
        const int t = tm + wm + mi * 16 + lg + r;
        float v = fmaxf(acc[mi][ni][r] + cbv, 0.f);
        if ((t & 511) > 512 - W) v = 0.f;  // window straddles answer boundary
        vmax = fmaxf(vmax, v);
      }
    vmax = fmaxf(vmax, __shfl_xor(vmax, 16));
    vmax = fmaxf(vmax, __shfl_xor(vmax, 32));
    if (lane < 16)
      atomicMax((int*)&cat[(size_t)n * 3072 + (W - 1) * 1024 + col], __float_as_int(vmax));
  }
}

// ---------------- attention S = pa @ pq^T  (split-K x4, deterministic partials) ----

__global__ __launch_bounds__(256, 2)
void attn_s(const u16* __restrict__ pa, float* __restrict__ Spart) {
  __shared__ alignas(16) u16 sA[128 * 32];
  __shared__ alignas(16) u16 sB[64 * 32];
  const int tid = threadIdx.x, lane = tid & 63;
  const int tm = blockIdx.x * 128;
  const int kbase = blockIdx.y * 256;     // K chunk of 256
  const int wid = tid >> 6;
  const int wm = (wid >> 1) * 64, wn = (wid & 1) * 32;
  const u16* pq = pa + (size_t)T_ANS * DIM;
  f32x4 acc[4][2] = {};
  for (int k0 = kbase; k0 < kbase + 256; k0 += 32) {
#pragma unroll
    for (int j = 0; j < 2; ++j) {
      const int f = tid * 16 + j * 4096;
      const int r = f >> 6, cb = f & 63;
      gl2lds16((const char*)pa + (size_t)(tm + r) * 2048 + k0 * 2 + cb, (char*)sA + f);
    }
    {
      const int f = tid * 16;  // 4 KB, single issue
      const int r = f >> 6, cb = f & 63;
      gl2lds16((const char*)pq + (size_t)r * 2048 + k0 * 2 + cb, (char*)sB + f);
    }
    __syncthreads();
    const int lr = lane & 15, lk = (lane >> 4) * 8;
    bf16x8 af[4], bfr[2];
#pragma unroll
    for (int i = 0; i < 4; ++i)
      af[i] = *(const bf16x8*)(sA + (wm + i * 16 + lr) * 32 + lk);
#pragma unroll
    for (int i = 0; i < 2; ++i)
      bfr[i] = *(const bf16x8*)(sB + (wn + i * 16 + lr) * 32 + lk);
#pragma unroll
    for (int mi = 0; mi < 4; ++mi)
#pragma unroll
      for (int ni = 0; ni < 2; ++ni)
        acc[mi][ni] = MF(af[mi], bfr[ni], acc[mi][ni]);
    __syncthreads();
  }
  const int lr = lane & 15, lg = (lane >> 4) * 4;
  float* Sp = Spart + (size_t)blockIdx.y * (T_ANS * 64);
#pragma unroll
  for (int mi = 0; mi < 4; ++mi)
#pragma unroll
    for (int ni = 0; ni < 2; ++ni)
#pragma unroll
      for (int r = 0; r < 4; ++r) {
        const int row = tm + wm + mi * 16 + lg + r;
        const int col = wn + ni * 16 + lr;
        Sp[(size_t)row * 64 + col] = acc[mi][ni][r];
      }
}

__global__ void softmax64(const float* __restrict__ Spart, u16* __restrict__ alpha) {
  const int row = blockIdx.x * 4 + (threadIdx.x >> 6);
  const int lane = threadIdx.x & 63;
  const size_t o = (size_t)row * 64 + lane;
  float v = Spart[o] + Spart[(size_t)1 * T_ANS * 64 + o]
          + Spart[(size_t)2 * T_ANS * 64 + o] + Spart[(size_t)3 * T_ANS * 64 + o];
  float m = v;
#pragma unroll
  for (int o2 = 32; o2 > 0; o2 >>= 1) m = fmaxf(m, __shfl_xor(m, o2));
  const float e = __expf(v - m);
  float s = e;
#pragma unroll
  for (int o2 = 32; o2 > 0; o2 >>= 1) s += __shfl_xor(s, o2);
  alpha[(size_t)row * 64 + lane] = f2bf(e / s);
}

// ---------------- Y = alpha @ pq ; sim = pa * Y ----------------

__global__ __launch_bounds__(256, 2)
void attn_y_sim(const u16* __restrict__ alpha, const u16* __restrict__ pqT,
                const u16* __restrict__ pa, u16* __restrict__ sim) {
  __shared__ alignas(16) u16 sA[128 * 32];
  __shared__ alignas(16) u16 sB[128 * 32];
  const int tid = threadIdx.x, lane = tid & 63;
  const int tm = blockIdx.x * 128, tn = blockIdx.y * 128;
  const int wid = tid >> 6;
  const int wm = (wid >> 1) * 64, wn = (wid & 1) * 64;
  f32x4 acc[4][4] = {};
  for (int k0 = 0; k0 < 64; k0 += 32) {
#pragma unroll
    for (int j = 0; j < 2; ++j) {
      const int f = tid * 16 + j * 4096;
      const int r = f >> 6, cb = f & 63;
      gl2lds16((const char*)alpha + (size_t)(tm + r) * 128 + k0 * 2 + cb, (char*)sA + f);
      gl2lds16((const char*)pqT   + (size_t)(tn + r) * 128 + k0 * 2 + cb, (char*)sB + f);
    }
    __syncthreads();
    const int lr = lane & 15, lk = (lane >> 4) * 8;
    bf16x8 af[4], bfr[4];
#pragma unroll
    for (int i = 0; i < 4; ++i) {
      af[i]  = *(const bf16x8*)(sA + (wm + i * 16 + lr) * 32 + lk);
      bfr[i] = *(const bf16x8*)(sB + (wn + i * 16 + lr) * 32 + lk);
    }
#pragma unroll
    for (int mi = 0; mi < 4; ++mi)
#pragma unroll
      for (int ni = 0; ni < 4; ++ni)
        acc[mi][ni] = MF(af[mi], bfr[ni], acc[mi][ni]);
    __syncthreads();
  }
  const int lr = lane & 15, lg = (lane >> 4) * 4;
#pragma unroll
  for (int ni = 0; ni < 4; ++ni) {
    const int col = tn + wn + ni * 16 + lr;
#pragma unroll
    for (int mi = 0; mi < 4; ++mi)
#pragma unroll
      for (int r = 0; r < 4; ++r) {
        const int row = tm + wm + mi * 16 + lg + r;
        const size_t o = (size_t)row * DIM + col;
        sim[o] = f2bf(bf2f(pa[o]) * acc[mi][ni][r]);
      }
  }
}

// ---------------- final: h = tanh(cat @ lin^T + b) ----------------

__global__ __launch_bounds__(256, 2)
void final_h(const u16* __restrict__ catb, const u16* __restrict__ linb,
             const float* __restrict__ lin_b, float* __restrict__ h) {
  __shared__ alignas(16) u16 sA[128 * 32];
  __shared__ alignas(16) u16 sB[128 * 32];
  const int tid = threadIdx.x, lane = tid & 63;
  const int tn = blockIdx.y * 128;
  const int wid = tid >> 6;
  const int wm = (wid >> 1) * 64, wn = (wid & 1) * 64;
  f32x4 acc[4][4] = {};
  for (int k0 = 0; k0 < 3072; k0 += 32) {
#pragma unroll
    for (int j = 0; j < 2; ++j) {
      const int f = tid * 16 + j * 4096;
      const int r = f >> 6, cb = f & 63;
      gl2lds16((const char*)catb + (size_t)r * 6144 + k0 * 2 + cb, (char*)sA + f);
      gl2lds16((const char*)linb + (size_t)(tn + r) * 6144 + k0 * 2 + cb, (char*)sB + f);
    }
    __syncthreads();
    const int lr = lane & 15, lk = (lane >> 4) * 8;
    bf16x8 af[4], bfr[4];
#pragma unroll
    for (int i = 0; i < 4; ++i) {
      af[i]  = *(const bf16x8*)(sA + (wm + i * 16 + lr) * 32 + lk);
      bfr[i] = *(const bf16x8*)(sB + (wn + i * 16 + lr) * 32 + lk);
    }
#pragma unroll
    for (int mi = 0; mi < 4; ++mi)
#pragma unroll
      for (int ni = 0; ni < 4; ++ni)
        acc[mi][ni] = MF(af[mi], bfr[ni], acc[mi][ni]);
    __syncthreads();
  }
  const int lr = lane & 15, lg = (lane >> 4) * 4;
#pragma unroll
  for (int ni = 0; ni < 4; ++ni) {
    const int col = tn + wn + ni * 16 + lr;
    const float bv = lin_b[col];
#pragma unroll
    for (int mi = 0; mi < 4; ++mi)
#pragma unroll
      for (int r = 0; r < 4; ++r) {
        const int row = wm + mi * 16 + lg + r;
        if (row < 64) {
          const float x = acc[mi][ni][r] + bv;
          h[(size_t)row * DIM + col] = 2.f / (1.f + __expf(-2.f * x)) - 1.f;
        }
      }
  }
}

__global__ void final_logits(const float* __restrict__ h, const float* __restrict__ soft_w,
                             const float* __restrict__ soft_b, float* __restrict__ out) {
  __shared__ float part[256];
  const int t = threadIdx.x;
  const int n = t >> 2, q = t & 3;
  float s = 0.f;
  for (int j = q * 256; j < q * 256 + 256; ++j) s += h[(size_t)n * DIM + j] * soft_w[j];
  part[t] = s;
  __syncthreads();
  if (t < 64) {
    float logit = part[t * 4] + part[t * 4 + 1] + part[t * 4 + 2] + part[t * 4 + 3] + soft_b[0];
    float m = logit;
#pragma unroll
    for (int o = 32; o > 0; o >>= 1) m = fmaxf(m, __shfl_xor(m, o));
    float e = __expf(logit - m);
    float ssum = e;
#pragma unroll
    for (int o = 32; o > 0; o >>= 1) ssum += __shfl_xor(ssum, o);
    out[t] = (logit - m) - logf(ssum);
  }
}

// ---------------- launcher ----------------

extern "C" void kernel_launch(void* const* d_in, const int* in_sizes, int n_in,
                              void* d_out, int out_size, void* d_ws, size_t ws_size,
                              hipStream_t stream) {
  const int*   data_q  = (const int*)d_in[0];
  const int*   data_as = (const int*)d_in[1];
  const float* emb     = (const float*)d_in[2];
  const float* w1      = (const float*)d_in[3];
  const float* b1      = (const float*)d_in[4];
  const float* w2      = (const float*)d_in[5];
  const float* b2      = (const float*)d_in[6];
  const float* cw1     = (const float*)d_in[7];
  const float* cb1     = (const float*)d_in[8];
  const float* cw2     = (const float*)d_in[9];
  const float* cb2     = (const float*)d_in[10];
  const float* cw3     = (const float*)d_in[11];
  const float* cb3     = (const float*)d_in[12];
  const float* lin_w   = (const float*)d_in[13];
  const float* lin_b   = (const float*)d_in[14];
  const float* soft_w  = (const float*)d_in[15];
  const float* soft_b  = (const float*)d_in[16];
  float* out = (float*)d_out;

  // allow 128 KiB dynamic LDS on the pipelined kernels (host attr set, capture-safe)
  hipFuncSetAttribute((const void*)proj_g, hipFuncAttributeMaxDynamicSharedMemorySize, 131072);
  hipFuncSetAttribute((const void*)conv_g<1>, hipFuncAttributeMaxDynamicSharedMemorySize, 131072);
  hipFuncSetAttribute((const void*)conv_g<2>, hipFuncAttributeMaxDynamicSharedMemorySize, 131072);
  hipFuncSetAttribute((const void*)conv_g<3>, hipFuncAttributeMaxDynamicSharedMemorySize, 131072);

  // workspace layout (~167 MB total)
  u16* X     = (u16*)d_ws;                         // [M_PAD][1024] bf16; reused: Spart, then sim
  u16* pa    = X    + (size_t)M_PAD * DIM;         // [M_PAD][1024] bf16 (rows T..T+63 = pq)
  u16* W12   = pa   + (size_t)M_PAD * DIM;         // [2048][1024] interleaved w1/w2
  u16* cwb   = W12  + (size_t)2 * 1024 * 1024;     // 6 x [1024][1024]
  u16* linb  = cwb  + (size_t)6 * 1024 * 1024;     // [1024][3072]
  u16* pqT   = linb + (size_t)3 * 1024 * 1024;     // [1024][64]
  u16* alpha = pqT  + 64 * 1024;                   // [T][64] bf16
  float* cat = (float*)(alpha + (size_t)T_ANS * 64);  // [64][3072] f32 pools
  u16* catb  = (u16*)(cat + 64 * 3072);            // [128][3072] bf16 (rows 64+ zero)
  float* h   = (float*)(catb + 128 * 3072);        // [64][1024] f32
  u16* simb  = X;                                  // alias: [T+2][1024] bf16
  float* Spart = (float*)X;                        // alias: [4][T][64] f32 (33.6 MB < 67 MB)

  hipMemsetAsync(cat, 0, 64 * 3072 * sizeof(float), stream);

  pack_w12<<<8192, 256, 0, stream>>>(w1, w2, W12);
  cast4<<<3072, 256, 0, stream>>>(lin_w, linb, 3072 * 1024 / 4);
  cast_conv_w<1><<<4096, 256, 0, stream>>>(cw1, cwb);
  cast_conv_w<2><<<4096, 256, 0, stream>>>(cw2, cwb + (size_t)1 * 1024 * 1024);
  cast_conv_w<3><<<4096, 256, 0, stream>>>(cw3, cwb + (size_t)3 * 1024 * 1024);

  gather_cast<<<M_PAD, 256, 0, stream>>>(data_q, data_as, emb, X);

  proj_g<<<1032, 512, 131072, stream>>>(X, W12, b1, b2, pa);
  transpose_pq<<<256, 256, 0, stream>>>(pa, pqT);

  attn_s<<<dim3(T_ANS / 128, 4), 256, 0, stream>>>(pa, Spart);
  softmax64<<<T_ANS / 4, 256, 0, stream>>>(Spart, alpha);
  attn_y_sim<<<dim3(T_ANS / 128, 8), 256, 0, stream>>>(alpha, pqT, pa, simb);
  zero_pad_sim<<<8, 256, 0, stream>>>(simb);

  conv_g<1><<<512, 512, 131072, stream>>>(simb, cwb, cb1, cat);
  conv_g<2><<<512, 512, 131072, stream>>>(simb, cwb + (size_t)1 * 1024 * 1024, cb2, cat);
  conv_g<3><<<512, 512, 131072, stream>>>(simb, cwb + (size_t)3 * 1024 * 1024, cb3, cat);

  cast_cat<<<1536, 256, 0, stream>>>(cat, catb);
  final_h<<<dim3(1, 8), 256, 0, stream>>>(catb, linb, lin_b, h);
  final_logits<<<1, 256, 0, stream>>>(h, soft_w, soft_b, out);
}

// Round 8
// 762.301 us; speedup vs baseline: 1.2210x; 1.0011x over previous
//
#include <hip/hip_runtime.h>

#define DEV __device__ __forceinline__

typedef __bf16 bf16x8 __attribute__((ext_vector_type(8)));
typedef float f32x4 __attribute__((ext_vector_type(4)));
typedef unsigned short u16;
typedef u16 u16x4 __attribute__((ext_vector_type(4)));

constexpr int T_ANS = 32768;        // N*La answer tokens
constexpr int LQ    = 64;
constexpr int M_ALL = T_ANS + LQ;   // 32832 rows fed to projection
constexpr int M_PAD = 33024;        // 129*256 (256-tile padded)
constexpr int DIM   = 1024;

DEV u16 f2bf(float x) {
  unsigned u = __float_as_uint(x);
  return (u16)((u + 0x7FFFu + ((u >> 16) & 1u)) >> 16);
}
DEV float bf2f(u16 s) { return __uint_as_float(((unsigned)s) << 16); }

DEV void gl2lds16(const void* g, void* l) {
  __builtin_amdgcn_global_load_lds(
      (const __attribute__((address_space(1))) unsigned int*)g,
      (__attribute__((address_space(3))) unsigned int*)l, 16, 0, 0);
}

#define MF(A, B, C) __builtin_amdgcn_mfma_f32_16x16x32_bf16(A, B, C, 0, 0, 0)

// ---------------- 4-phase/K-tile 256x256 GEMM core, COUNTED vmcnt (T4) -----------
// LDS: [A0 32K][B0 32K][A1 32K][B1 32K]. Rows 128 B, swizzle block ^= (row&7).
// Stage placement: PH0(t): B(t+1) x4; PH1(t): A-chunks 0,2 (rows 0-63,128-191);
// PH2(t): A-chunks 1,3 (rows 64-127,192-255).
// Reads: PH0 uses B(t)+A-chunks0/2(t); PH2/PH3 use A-chunks1/3(t).
// Counted waits (per-wave queue, oldest-first): end-PH1: vmcnt(6) drains A1,A3(t);
// end-PH3: vmcnt(2) drains B(t+1),A0,A2(t+1) and leaves A1,A3(t+1) in flight.
// Never drains to 0 in the main loop (m218's isolated +38-73% lever). Last tile
// peeled: no stages, vmcnt(0) at PH1.

#define LFC(BASE, OFF) (*(const bf16x8*)((BASE) + (OFF)))

#define STG(G, LT, R0) gl2lds16((G) + (R0) * 2048 + gOff, (LT) + (R0) * 128 + tidOff)

// k-half-major MFMA order: 8 independent accs per half -> chain distance 8
#define MQUAD(Q, a00, a01, a10, a11)                                                  \
    acc[2*(Q)][0]   = MF(a00, bb00, acc[2*(Q)][0]);                                   \
    acc[2*(Q)][1]   = MF(a00, bb10, acc[2*(Q)][1]);                                   \
    acc[2*(Q)][2]   = MF(a00, bb20, acc[2*(Q)][2]);                                   \
    acc[2*(Q)][3]   = MF(a00, bb30, acc[2*(Q)][3]);                                   \
    acc[2*(Q)+1][0] = MF(a10, bb00, acc[2*(Q)+1][0]);                                 \
    acc[2*(Q)+1][1] = MF(a10, bb10, acc[2*(Q)+1][1]);                                 \
    acc[2*(Q)+1][2] = MF(a10, bb20, acc[2*(Q)+1][2]);                                 \
    acc[2*(Q)+1][3] = MF(a10, bb30, acc[2*(Q)+1][3]);                                 \
    acc[2*(Q)][0]   = MF(a01, bb01, acc[2*(Q)][0]);                                   \
    acc[2*(Q)][1]   = MF(a01, bb11, acc[2*(Q)][1]);                                   \
    acc[2*(Q)][2]   = MF(a01, bb21, acc[2*(Q)][2]);                                   \
    acc[2*(Q)][3]   = MF(a01, bb31, acc[2*(Q)][3]);                                   \
    acc[2*(Q)+1][0] = MF(a11, bb01, acc[2*(Q)+1][0]);                                 \
    acc[2*(Q)+1][1] = MF(a11, bb11, acc[2*(Q)+1][1]);                                 \
    acc[2*(Q)+1][2] = MF(a11, bb21, acc[2*(Q)+1][2]);                                 \
    acc[2*(Q)+1][3] = MF(a11, bb31, acc[2*(Q)+1][3]);

#define BARW                                                                          \
    __builtin_amdgcn_s_barrier();                                                     \
    asm volatile("s_waitcnt lgkmcnt(0)" ::: "memory");                                \
    __builtin_amdgcn_sched_barrier(0);

#define VMW0 asm volatile("s_waitcnt vmcnt(0)" ::: "memory"); __builtin_amdgcn_sched_barrier(0);
#define VMW2 asm volatile("s_waitcnt vmcnt(2)" ::: "memory"); __builtin_amdgcn_sched_barrier(0);
#define VMW6 asm volatile("s_waitcnt vmcnt(6)" ::: "memory"); __builtin_amdgcn_sched_barrier(0);

// One K-tile = 4 phases. SB/SA02/SA13 = stage groups for tile t+1; W1/W3 = counted waits.
#define TILE(Ac0, Ac1, Bc0, Bc1, SB, SA02, SA13, W1, W3)                              \
  { /* PH0: all B + A quadrant 0 */                                                   \
    bb00 = LFC(Bc0, 0);    bb01 = LFC(Bc1, 0);                                        \
    bb10 = LFC(Bc0, 2048); bb11 = LFC(Bc1, 2048);                                     \
    bb20 = LFC(Bc0, 4096); bb21 = LFC(Bc1, 4096);                                     \
    bb30 = LFC(Bc0, 6144); bb31 = LFC(Bc1, 6144);                                     \
    bf16x8 a00 = LFC(Ac0, 0),    a01 = LFC(Ac1, 0);                                   \
    bf16x8 a10 = LFC(Ac0, 2048), a11 = LFC(Ac1, 2048);                                \
    SB                                                                                \
    asm volatile("s_waitcnt lgkmcnt(8)" ::: "memory");                                \
    BARW                                                                              \
    __builtin_amdgcn_s_setprio(1); MQUAD(0, a00, a01, a10, a11)                       \
    __builtin_amdgcn_s_setprio(0);                                                    \
    __builtin_amdgcn_s_barrier();                                                     \
  }                                                                                   \
  { /* PH1 */                                                                         \
    bf16x8 a00 = LFC(Ac0, 4096), a01 = LFC(Ac1, 4096);                                \
    bf16x8 a10 = LFC(Ac0, 6144), a11 = LFC(Ac1, 6144);                                \
    SA02                                                                              \
    BARW                                                                              \
    __builtin_amdgcn_s_setprio(1); MQUAD(1, a00, a01, a10, a11)                       \
    __builtin_amdgcn_s_setprio(0);                                                    \
    W1                                                                                \
    __builtin_amdgcn_s_barrier();                                                     \
  }                                                                                   \
  { /* PH2 */                                                                         \
    bf16x8 a00 = LFC(Ac0, 8192),  a01 = LFC(Ac1, 8192);                               \
    bf16x8 a10 = LFC(Ac0, 10240), a11 = LFC(Ac1, 10240);                              \
    SA13                                                                              \
    BARW                                                                              \
    __builtin_amdgcn_s_setprio(1); MQUAD(2, a00, a01, a10, a11)                       \
    __builtin_amdgcn_s_setprio(0);                                                    \
    __builtin_amdgcn_s_barrier();                                                     \
  }                                                                                   \
  { /* PH3 */                                                                         \
    bf16x8 a00 = LFC(Ac0, 12288), a01 = LFC(Ac1, 12288);                              \
    bf16x8 a10 = LFC(Ac0, 14336), a11 = LFC(Ac1, 14336);                              \
    BARW                                                                              \
    __builtin_amdgcn_s_setprio(1); MQUAD(3, a00, a01, a10, a11)                       \
    __builtin_amdgcn_s_setprio(0);                                                    \
    W3                                                                                \
    __builtin_amdgcn_s_barrier();                                                     \
  }

#define S_FULL(G, LT) { const char* g_ = (G); STG(g_, LT, 0); STG(g_, LT, 64); STG(g_, LT, 128); STG(g_, LT, 192); }
#define S_A02(G, LT)  { const char* g_ = (G); STG(g_, LT, 0); STG(g_, LT, 128); }
#define S_A13(G, LT)  { const char* g_ = (G); STG(g_, LT, 64); STG(g_, LT, 192); }

// KT K-tiles of 64; buffers ping-pong; last tile peeled (no stage, full drain at PH1).
#define GEMM_PIPE(KT)                                                                 \
  f32x4 acc[8][4] = {};                                                               \
  bf16x8 bb00, bb01, bb10, bb11, bb20, bb21, bb30, bb31;                              \
  const int e_ = lane & 7, h_ = lane >> 4, blk0 = (h_ ^ e_) << 4, blk1 = ((h_ ^ e_) ^ 4) << 4; \
  const int rA0 = (wm + lr) * 128, rB0 = (wn + lr) * 128;                             \
  const char* A0c0 = lds + rA0 + blk0;          const char* A0c1 = lds + rA0 + blk1;  \
  const char* B0c0 = lds + 32768 + rB0 + blk0;  const char* B0c1 = lds + 32768 + rB0 + blk1; \
  const char* A1c0 = lds + 65536 + rA0 + blk0;  const char* A1c1 = lds + 65536 + rA0 + blk1; \
  const char* B1c0 = lds + 98304 + rB0 + blk0;  const char* B1c1 = lds + 98304 + rB0 + blk1; \
  char* ldsA0 = lds;          char* ldsB0 = lds + 32768;                              \
  char* ldsA1 = lds + 65536;  char* ldsB1 = lds + 98304;                              \
  const int tidOff = tid * 16;                                                        \
  const int gOff = (tid >> 3) * 2048 + (((tid & 7) ^ ((tid >> 3) & 7)) << 4);         \
  S_FULL(Ab(0), ldsA0) S_FULL(Bb(0), ldsB0)                                           \
  VMW0                                                                                \
  __builtin_amdgcn_s_barrier();                                                       \
  for (int kp = 0; kp < (KT) / 2 - 1; ++kp) {                                         \
    const int k1 = 2 * kp + 1;                                                        \
    TILE(A0c0, A0c1, B0c0, B0c1,                                                      \
         S_FULL(Bb(k1), ldsB1), S_A02(Ab(k1), ldsA1), S_A13(Ab(k1), ldsA1),           \
         VMW6, VMW2)                                                                  \
    TILE(A1c0, A1c1, B1c0, B1c1,                                                      \
         S_FULL(Bb(k1 + 1), ldsB0), S_A02(Ab(k1 + 1), ldsA0), S_A13(Ab(k1 + 1), ldsA0), \
         VMW6, VMW2)                                                                  \
  }                                                                                   \
  TILE(A0c0, A0c1, B0c0, B0c1,                                                        \
       S_FULL(Bb((KT) - 1), ldsB1), S_A02(Ab((KT) - 1), ldsA1), S_A13(Ab((KT) - 1), ldsA1), \
       VMW6, VMW2)                                                                    \
  TILE(A1c0, A1c1, B1c0, B1c1, , , , VMW0, )

// ---------------- simple cast / gather kernels ----------------

__global__ void cast4(const float* __restrict__ src, u16* __restrict__ dst, int n4) {
  int i = blockIdx.x * 256 + threadIdx.x;
  if (i < n4) {
    float4 v = ((const float4*)src)[i];
    u16x4 o = { f2bf(v.x), f2bf(v.y), f2bf(v.z), f2bf(v.w) };
    ((u16x4*)dst)[i] = o;
  }
}

// cw[o][i][k] (stride W in k) -> W matrices BT_k[o][i], k-major contiguous reads
template<int W>
__global__ void cast_conv_w(const float* __restrict__ src, u16* __restrict__ dst) {
  int i = blockIdx.x * 256 + threadIdx.x;  // over 1024*1024
  if (i < 1024 * 1024) {
#pragma unroll
    for (int k = 0; k < W; ++k)
      dst[(size_t)k * (1024 * 1024) + i] = f2bf(src[(size_t)i * W + k]);
  }
}

// W12 pack: 16-row interleave of w1/w2 so a 256-wide N-tile holds matched pairs
__global__ void pack_w12(const float* __restrict__ w1, const float* __restrict__ w2,
                         u16* __restrict__ W12) {
  int i = blockIdx.x * 256 + threadIdx.x;  // over 2048*1024
  if (i < 2048 * 1024) {
    int n2 = i >> 10, k = i & 1023;
    int j = n2 >> 4, m = n2 & 15;
    const float* src = (j & 1) ? w2 : w1;
    W12[i] = f2bf(src[(size_t)((j >> 1) * 16 + m) * 1024 + k]);
  }
}

__global__ void gather_cast(const int* __restrict__ dq, const int* __restrict__ das,
                            const float* __restrict__ emb, u16* __restrict__ X) {
  const int row = blockIdx.x;        // [0, M_PAD)
  const int c   = threadIdx.x;       // 256 threads * 4 floats = 1024
  size_t dsto = (size_t)row * DIM + c * 4;
  if (row >= M_ALL) {                // zero pad rows so GEMM tiles are clean
    u16x4 z = {0, 0, 0, 0};
    *(u16x4*)(X + dsto) = z;
    return;
  }
  const int tok = (row < T_ANS) ? das[row] : dq[row - T_ANS];
  float4 v = ((const float4*)(emb + (size_t)tok * DIM))[c];
  u16x4 o = { f2bf(v.x), f2bf(v.y), f2bf(v.z), f2bf(v.w) };
  *(u16x4*)(X + dsto) = o;
}

__global__ void transpose_pq(const u16* __restrict__ pa, u16* __restrict__ pqT) {
  int i = blockIdx.x * 256 + threadIdx.x;  // 1024*64
  int e = i >> 6, q = i & 63;
  pqT[i] = pa[(size_t)(T_ANS + q) * DIM + e];
}

__global__ void zero_pad_sim(u16* __restrict__ sim) {
  int i = blockIdx.x * 256 + threadIdx.x;
  if (i < 2 * DIM) sim[(size_t)T_ANS * DIM + i] = 0;
}

__global__ void cast_cat(const float* __restrict__ cat, u16* __restrict__ catb) {
  int i = blockIdx.x * 256 + threadIdx.x;  // 128*3072
  if (i < 128 * 3072) {
    int row = i / 3072;
    catb[i] = (row < 64) ? f2bf(cat[i]) : (u16)0;
  }
}

// ---------------- projection: pa = sig(X@w1^T+b1)*tanh(X@w2^T+b2) ------------------
// One GEMM M=33024, N=2048 (interleaved W12), K=1024 (KT=16). 1D grid 1032, XCD-swizzled.

__global__ __launch_bounds__(512, 1)
void proj_g(const u16* __restrict__ X, const u16* __restrict__ W12,
            const float* __restrict__ b1, const float* __restrict__ b2,
            u16* __restrict__ pa) {
  extern __shared__ char lds[];
  const int tid = threadIdx.x, lane = tid & 63;
  const int wid = tid >> 6;
  const int wm = (wid >> 2) * 128, wn = (wid & 3) * 64;
  const int lr = lane & 15;
  // bijective XCD swizzle: 1032 = 8*129; same-A blocks (all 8 tn) contiguous per XCD
  const int wg = ((int)blockIdx.x % 8) * 129 + (int)blockIdx.x / 8;
  const int tm = (wg >> 3) * 256, tn = (wg & 7) * 256;
  const char* Ag = (const char*)X + (size_t)tm * 2048;
  const char* Bg = (const char*)W12 + (size_t)tn * 2048;
  auto Ab = [&](int kt) { return Ag + ((kt & 15) << 7); };
  auto Bb = [&](int kt) { return Bg + ((kt & 15) << 7); };

  GEMM_PIPE(16)

  // epilogue: gate, then LDS bounce (stride 132 u16), then coalesced u16x4 streams
  u16* cw = (u16*)lds;
  const int lg = (lane >> 4) * 4;
#pragma unroll
  for (int pp = 0; pp < 2; ++pp) {
    const int clocal = ((wn >> 5) + pp) * 16 + lr;   // 0..127
    const int col = (tn >> 1) + clocal;
    const float b1v = b1[col], b2v = b2[col];
#pragma unroll
    for (int mi = 0; mi < 8; ++mi)
#pragma unroll
      for (int r = 0; r < 4; ++r) {
        const int rowL = wm + mi * 16 + lg + r;
        const float x1 = acc[mi][2 * pp][r] + b1v;
        const float x2 = acc[mi][2 * pp + 1][r] + b2v;
        const float sg = 1.f / (1.f + __expf(-x1));
        const float th = 2.f / (1.f + __expf(-2.f * x2)) - 1.f;
        cw[rowL * 132 + clocal] = f2bf(sg * th);
      }
  }
  __syncthreads();
#pragma unroll
  for (int it = 0; it < 16; ++it) {
    const int cid = it * 512 + tid;                  // 8192 chunks of 4 u16
    const int rowL = cid >> 5, c4 = (cid & 31) * 4;
    u16x4 v = *(const u16x4*)(cw + rowL * 132 + c4);
    *(u16x4*)(pa + (size_t)(tm + rowL) * DIM + (tn >> 1) + c4) = v;
  }
}

// ---------------- conv (window W) + relu + per-answer DMax -------------------------
// GEMM M=32768, N=1024, K=W*1024; tap = kt/16 shifts A rows & selects B slab.

template<int W>
__global__ __launch_bounds__(512, 1)
void conv_g(const u16* __restrict__ sim, const u16* __restrict__ Bw,
            const float* __restrict__ cb, float* __restrict__ cat) {
  extern __shared__ char lds[];
  const int tid = threadIdx.x, lane = tid & 63;
  const int wid = tid >> 6;
  const int wm = (wid >> 2) * 128, wn = (wid & 3) * 64;
  const int lr = lane & 15;
  // bijective XCD swizzle: 512 = 8*64; same-A blocks (all 4 tn) contiguous per XCD
  const int wg = ((int)blockIdx.x % 8) * 64 + (int)blockIdx.x / 8;
  const int tm = (wg >> 2) * 256, tn = (wg & 3) * 256;
  const char* Ag = (const char*)sim + (size_t)tm * 2048;
  const char* Bg = (const char*)Bw + (size_t)tn * 2048;
  auto Ab = [&](int kt) { return Ag + (kt >> 4) * 2048 + ((kt & 15) << 7); };
  auto Bb = [&](int kt) { return Bg + (size_t)(kt >> 4) * 2097152 + ((kt & 15) << 7); };

  GEMM_PIPE(16 * W)

  // epilogue: +cb, relu, mask boundary rows, column max, atomicMax into cat
  const int lg = (lane >> 4) * 4;
  const int n = tm >> 9;  // 256 | 512 so one answer per tile
#pragma unroll
  for (int ni = 0; ni < 4; ++ni) {
    const int col = tn + wn + ni * 16 + lr;
    const float cbv = cb[col];
    float vmax = 0.f;
#pragma unroll
    for (int mi = 0; mi < 8; ++mi)
#pragma unroll
      for (int r = 0; r < 4; ++r) {
        const int t = tm + wm + mi * 16 + lg + r;
        float v = fmaxf(acc[mi][ni][r] + cbv, 0.f);
        if ((t & 511) > 512 - W) v = 0.f;  // window straddles answer boundary
        vmax = fmaxf(vmax, v);
      }
    vmax = fmaxf(vmax, __shfl_xor(vmax, 16));
    vmax = fmaxf(vmax, __shfl_xor(vmax, 32));
    if (lane < 16)
      atomicMax((int*)&cat[(size_t)n * 3072 + (W - 1) * 1024 + col], __float_as_int(vmax));
  }
}

// ---------------- attention S = pa @ pq^T  (split-K x4, deterministic partials) ----

__global__ __launch_bounds__(256, 2)
void attn_s(const u16* __restrict__ pa, float* __restrict__ Spart) {
  __shared__ alignas(16) u16 sA[128 * 32];
  __shared__ alignas(16) u16 sB[64 * 32];
  const int tid = threadIdx.x, lane = tid & 63;
  const int tm = blockIdx.x * 128;
  const int kbase = blockIdx.y * 256;     // K chunk of 256
  const int wid = tid >> 6;
  const int wm = (wid >> 1) * 64, wn = (wid & 1) * 32;
  const u16* pq = pa + (size_t)T_ANS * DIM;
  f32x4 acc[4][2] = {};
  for (int k0 = kbase; k0 < kbase + 256; k0 += 32) {
#pragma unroll
    for (int j = 0; j < 2; ++j) {
      const int f = tid * 16 + j * 4096;
      const int r = f >> 6, cb = f & 63;
      gl2lds16((const char*)pa + (size_t)(tm + r) * 2048 + k0 * 2 + cb, (char*)sA + f);
    }
    {
      const int f = tid * 16;  // 4 KB, single issue
      const int r = f >> 6, cb = f & 63;
      gl2lds16((const char*)pq + (size_t)r * 2048 + k0 * 2 + cb, (char*)sB + f);
    }
    __syncthreads();
    const int lr = lane & 15, lk = (lane >> 4) * 8;
    bf16x8 af[4], bfr[2];
#pragma unroll
    for (int i = 0; i < 4; ++i)
      af[i] = *(const bf16x8*)(sA + (wm + i * 16 + lr) * 32 + lk);
#pragma unroll
    for (int i = 0; i < 2; ++i)
      bfr[i] = *(const bf16x8*)(sB + (wn + i * 16 + lr) * 32 + lk);
#pragma unroll
    for (int mi = 0; mi < 4; ++mi)
#pragma unroll
      for (int ni = 0; ni < 2; ++ni)
        acc[mi][ni] = MF(af[mi], bfr[ni], acc[mi][ni]);
    __syncthreads();
  }
  const int lr = lane & 15, lg = (lane >> 4) * 4;
  float* Sp = Spart + (size_t)blockIdx.y * (T_ANS * 64);
#pragma unroll
  for (int mi = 0; mi < 4; ++mi)
#pragma unroll
    for (int ni = 0; ni < 2; ++ni)
#pragma unroll
      for (int r = 0; r < 4; ++r) {
        const int row = tm + wm + mi * 16 + lg + r;
        const int col = wn + ni * 16 + lr;
        Sp[(size_t)row * 64 + col] = acc[mi][ni][r];
      }
}

__global__ void softmax64(const float* __restrict__ Spart, u16* __restrict__ alpha) {
  const int row = blockIdx.x * 4 + (threadIdx.x >> 6);
  const int lane = threadIdx.x & 63;
  const size_t o = (size_t)row * 64 + lane;
  float v = Spart[o] + Spart[(size_t)1 * T_ANS * 64 + o]
          + Spart[(size_t)2 * T_ANS * 64 + o] + Spart[(size_t)3 * T_ANS * 64 + o];
  float m = v;
#pragma unroll
  for (int o2 = 32; o2 > 0; o2 >>= 1) m = fmaxf(m, __shfl_xor(m, o2));
  const float e = __expf(v - m);
  float s = e;
#pragma unroll
  for (int o2 = 32; o2 > 0; o2 >>= 1) s += __shfl_xor(s, o2);
  alpha[(size_t)row * 64 + lane] = f2bf(e / s);
}

// ---------------- Y = alpha @ pq ; sim = pa * Y ----------------

__global__ __launch_bounds__(256, 2)
void attn_y_sim(const u16* __restrict__ alpha, const u16* __restrict__ pqT,
                const u16* __restrict__ pa, u16* __restrict__ sim) {
  __shared__ alignas(16) u16 sA[128 * 32];
  __shared__ alignas(16) u16 sB[128 * 32];
  const int tid = threadIdx.x, lane = tid & 63;
  const int tm = blockIdx.x * 128, tn = blockIdx.y * 128;
  const int wid = tid >> 6;
  const int wm = (wid >> 1) * 64, wn = (wid & 1) * 64;
  f32x4 acc[4][4] = {};
  for (int k0 = 0; k0 < 64; k0 += 32) {
#pragma unroll
    for (int j = 0; j < 2; ++j) {
      const int f = tid * 16 + j * 4096;
      const int r = f >> 6, cb = f & 63;
      gl2lds16((const char*)alpha + (size_t)(tm + r) * 128 + k0 * 2 + cb, (char*)sA + f);
      gl2lds16((const char*)pqT   + (size_t)(tn + r) * 128 + k0 * 2 + cb, (char*)sB + f);
    }
    __syncthreads();
    const int lr = lane & 15, lk = (lane >> 4) * 8;
    bf16x8 af[4], bfr[4];
#pragma unroll
    for (int i = 0; i < 4; ++i) {
      af[i]  = *(const bf16x8*)(sA + (wm + i * 16 + lr) * 32 + lk);
      bfr[i] = *(const bf16x8*)(sB + (wn + i * 16 + lr) * 32 + lk);
    }
#pragma unroll
    for (int mi = 0; mi < 4; ++mi)
#pragma unroll
      for (int ni = 0; ni < 4; ++ni)
        acc[mi][ni] = MF(af[mi], bfr[ni], acc[mi][ni]);
    __syncthreads();
  }
  const int lr = lane & 15, lg = (lane >> 4) * 4;
#pragma unroll
  for (int ni = 0; ni < 4; ++ni) {
    const int col = tn + wn + ni * 16 + lr;
#pragma unroll
    for (int mi = 0; mi < 4; ++mi)
#pragma unroll
      for (int r = 0; r < 4; ++r) {
        const int row = tm + wm + mi * 16 + lg + r;
        const size_t o = (size_t)row * DIM + col;
        sim[o] = f2bf(bf2f(pa[o]) * acc[mi][ni][r]);
      }
  }
}

// ---------------- final: h = tanh(cat @ lin^T + b) ----------------

__global__ __launch_bounds__(256, 2)
void final_h(const u16* __restrict__ catb, const u16* __restrict__ linb,
             const float* __restrict__ lin_b, float* __restrict__ h) {
  __shared__ alignas(16) u16 sA[128 * 32];
  __shared__ alignas(16) u16 sB[128 * 32];
  const int tid = threadIdx.x, lane = tid & 63;
  const int tn = blockIdx.y * 128;
  const int wid = tid >> 6;
  const int wm = (wid >> 1) * 64, wn = (wid & 1) * 64;
  f32x4 acc[4][4] = {};
  for (int k0 = 0; k0 < 3072; k0 += 32) {
#pragma unroll
    for (int j = 0; j < 2; ++j) {
      const int f = tid * 16 + j * 4096;
      const int r = f >> 6, cb = f & 63;
      gl2lds16((const char*)catb + (size_t)r * 6144 + k0 * 2 + cb, (char*)sA + f);
      gl2lds16((const char*)linb + (size_t)(tn + r) * 6144 + k0 * 2 + cb, (char*)sB + f);
    }
    __syncthreads();
    const int lr = lane & 15, lk = (lane >> 4) * 8;
    bf16x8 af[4], bfr[4];
#pragma unroll
    for (int i = 0; i < 4; ++i) {
      af[i]  = *(const bf16x8*)(sA + (wm + i * 16 + lr) * 32 + lk);
      bfr[i] = *(const bf16x8*)(sB + (wn + i * 16 + lr) * 32 + lk);
    }
#pragma unroll
    for (int mi = 0; mi < 4; ++mi)
#pragma unroll
      for (int ni = 0; ni < 4; ++ni)
        acc[mi][ni] = MF(af[mi], bfr[ni], acc[mi][ni]);
    __syncthreads();
  }
  const int lr = lane & 15, lg = (lane >> 4) * 4;
#pragma unroll
  for (int ni = 0; ni < 4; ++ni) {
    const int col = tn + wn + ni * 16 + lr;
    const float bv = lin_b[col];
#pragma unroll
    for (int mi = 0; mi < 4; ++mi)
#pragma unroll
      for (int r = 0; r < 4; ++r) {
        const int row = wm + mi * 16 + lg + r;
        if (row < 64) {
          const float x = acc[mi][ni][r] + bv;
          h[(size_t)row * DIM + col] = 2.f / (1.f + __expf(-2.f * x)) - 1.f;
        }
      }
  }
}

__global__ void final_logits(const float* __restrict__ h, const float* __restrict__ soft_w,
                             const float* __restrict__ soft_b, float* __restrict__ out) {
  __shared__ float part[256];
  const int t = threadIdx.x;
  const int n = t >> 2, q = t & 3;
  float s = 0.f;
  for (int j = q * 256; j < q * 256 + 256; ++j) s += h[(size_t)n * DIM + j] * soft_w[j];
  part[t] = s;
  __syncthreads();
  if (t < 64) {
    float logit = part[t * 4] + part[t * 4 + 1] + part[t * 4 + 2] + part[t * 4 + 3] + soft_b[0];
    float m = logit;
#pragma unroll
    for (int o = 32; o > 0; o >>= 1) m = fmaxf(m, __shfl_xor(m, o));
    float e = __expf(logit - m);
    float ssum = e;
#pragma unroll
    for (int o = 32; o > 0; o >>= 1) ssum += __shfl_xor(ssum, o);
    out[t] = (logit - m) - logf(ssum);
  }
}

// ---------------- launcher ----------------

extern "C" void kernel_launch(void* const* d_in, const int* in_sizes, int n_in,
                              void* d_out, int out_size, void* d_ws, size_t ws_size,
                              hipStream_t stream) {
  const int*   data_q  = (const int*)d_in[0];
  const int*   data_as = (const int*)d_in[1];
  const float* emb     = (const float*)d_in[2];
  const float* w1      = (const float*)d_in[3];
  const float* b1      = (const float*)d_in[4];
  const float* w2      = (const float*)d_in[5];
  const float* b2      = (const float*)d_in[6];
  const float* cw1     = (const float*)d_in[7];
  const float* cb1     = (const float*)d_in[8];
  const float* cw2     = (const float*)d_in[9];
  const float* cb2     = (const float*)d_in[10];
  const float* cw3     = (const float*)d_in[11];
  const float* cb3     = (const float*)d_in[12];
  const float* lin_w   = (const float*)d_in[13];
  const float* lin_b   = (const float*)d_in[14];
  const float* soft_w  = (const float*)d_in[15];
  const float* soft_b  = (const float*)d_in[16];
  float* out = (float*)d_out;

  // allow 128 KiB dynamic LDS on the pipelined kernels (host attr set, capture-safe)
  hipFuncSetAttribute((const void*)proj_g, hipFuncAttributeMaxDynamicSharedMemorySize, 131072);
  hipFuncSetAttribute((const void*)conv_g<1>, hipFuncAttributeMaxDynamicSharedMemorySize, 131072);
  hipFuncSetAttribute((const void*)conv_g<2>, hipFuncAttributeMaxDynamicSharedMemorySize, 131072);
  hipFuncSetAttribute((const void*)conv_g<3>, hipFuncAttributeMaxDynamicSharedMemorySize, 131072);

  // workspace layout (~167 MB total)
  u16* X     = (u16*)d_ws;                         // [M_PAD][1024] bf16; reused: Spart, then sim
  u16* pa    = X    + (size_t)M_PAD * DIM;         // [M_PAD][1024] bf16 (rows T..T+63 = pq)
  u16* W12   = pa   + (size_t)M_PAD * DIM;         // [2048][1024] interleaved w1/w2
  u16* cwb   = W12  + (size_t)2 * 1024 * 1024;     // 6 x [1024][1024]
  u16* linb  = cwb  + (size_t)6 * 1024 * 1024;     // [1024][3072]
  u16* pqT   = linb + (size_t)3 * 1024 * 1024;     // [1024][64]
  u16* alpha = pqT  + 64 * 1024;                   // [T][64] bf16
  float* cat = (float*)(alpha + (size_t)T_ANS * 64);  // [64][3072] f32 pools
  u16* catb  = (u16*)(cat + 64 * 3072);            // [128][3072] bf16 (rows 64+ zero)
  float* h   = (float*)(catb + 128 * 3072);        // [64][1024] f32
  u16* simb  = X;                                  // alias: [T+2][1024] bf16
  float* Spart = (float*)X;                        // alias: [4][T][64] f32 (33.6 MB < 67 MB)

  hipMemsetAsync(cat, 0, 64 * 3072 * sizeof(float), stream);

  pack_w12<<<8192, 256, 0, stream>>>(w1, w2, W12);
  cast4<<<3072, 256, 0, stream>>>(lin_w, linb, 3072 * 1024 / 4);
  cast_conv_w<1><<<4096, 256, 0, stream>>>(cw1, cwb);
  cast_conv_w<2><<<4096, 256, 0, stream>>>(cw2, cwb + (size_t)1 * 1024 * 1024);
  cast_conv_w<3><<<4096, 256, 0, stream>>>(cw3, cwb + (size_t)3 * 1024 * 1024);

  gather_cast<<<M_PAD, 256, 0, stream>>>(data_q, data_as, emb, X);

  proj_g<<<1032, 512, 131072, stream>>>(X, W12, b1, b2, pa);
  transpose_pq<<<256, 256, 0, stream>>>(pa, pqT);

  attn_s<<<dim3(T_ANS / 128, 4), 256, 0, stream>>>(pa, Spart);
  softmax64<<<T_ANS / 4, 256, 0, stream>>>(Spart, alpha);
  attn_y_sim<<<dim3(T_ANS / 128, 8), 256, 0, stream>>>(alpha, pqT, pa, simb);
  zero_pad_sim<<<8, 256, 0, stream>>>(simb);

  conv_g<1><<<512, 512, 131072, stream>>>(simb, cwb, cb1, cat);
  conv_g<2><<<512, 512, 131072, stream>>>(simb, cwb + (size_t)1 * 1024 * 1024, cb2, cat);
  conv_g<3><<<512, 512, 131072, stream>>>(simb, cwb + (size_t)3 * 1024 * 1024, cb3, cat);

  cast_cat<<<1536, 256, 0, stream>>>(cat, catb);
  final_h<<<dim3(1, 8), 256, 0, stream>>>(catb, linb, lin_b, h);
  final_logits<<<1, 256, 0, stream>>>(h, soft_w, soft_b, out);
}